// Round 6
// baseline (1157.573 us; speedup 1.0000x reference)
//
#include <hip/hip_runtime.h>
#include <math.h>

#define NTOK 32768
typedef unsigned short ushort_t;

// d_out offsets (in floats)
#define OFF_CENT 0
#define OFF_SE   131072
#define OFF_WC   16908288
#define OFF_SC   16973824
#define OFF_OT   17039360
#define OFF_CT   17072128
#define OFF_OI   17072640
#define OFF_CI   17105408

typedef __attribute__((ext_vector_type(8))) short short8v;
typedef __attribute__((ext_vector_type(4))) float f32x4;
typedef __attribute__((ext_vector_type(16))) float f32x16;

__device__ __forceinline__ float dot4(float4 a, float4 b){
    return a.x*b.x + a.y*b.y + a.z*b.z + a.w*b.w;
}

// RNE float -> bf16 bits
__device__ __forceinline__ ushort_t f2bf(float x){
    unsigned int u = __float_as_uint(x);
    unsigned int r = (u + 0x7fffu + ((u >> 16) & 1u)) >> 16;
    return (ushort_t)r;
}
__device__ __forceinline__ float bf2f(ushort_t h){
    return __uint_as_float(((unsigned int)h) << 16);
}

__device__ __forceinline__ void gload16(const void* g, void* l){
    __builtin_amdgcn_global_load_lds(
        (const __attribute__((address_space(1))) void*)g,
        (__attribute__((address_space(3))) void*)l,
        16, 0, 0);
}

// ---------------- centroids: tanh + c2 + hi/lo split ----------------
__global__ __launch_bounds__(64) void k_cent(const float* __restrict__ raw,
                                             float* __restrict__ out,
                                             float* __restrict__ c2,
                                             ushort_t* __restrict__ ch,
                                             ushort_t* __restrict__ cl)
{
    int c = blockIdx.x, l = threadIdx.x;
    float4 v = *(const float4*)(raw + (size_t)c*256 + l*4);
    float4 t;
    t.x = tanhf(v.x); t.y = tanhf(v.y); t.z = tanhf(v.z); t.w = tanhf(v.w);
    *(float4*)(out + OFF_CENT + (size_t)c*256 + l*4) = t;
    ushort4 h = make_ushort4(f2bf(t.x), f2bf(t.y), f2bf(t.z), f2bf(t.w));
    ushort4 lo = make_ushort4(f2bf(t.x - bf2f(h.x)), f2bf(t.y - bf2f(h.y)),
                              f2bf(t.z - bf2f(h.z)), f2bf(t.w - bf2f(h.w)));
    *(ushort4*)(ch + (size_t)c*256 + l*4) = h;
    *(ushort4*)(cl + (size_t)c*256 + l*4) = lo;
    float s = dot4(t, t);
    #pragma unroll
    for (int off = 32; off > 0; off >>= 1) s += __shfl_down(s, off);
    if (l == 0) c2[c] = s;
}

// ---------------- word_class fill ----------------
__global__ __launch_bounds__(256) void k_wc(float* __restrict__ out)
{
    int g = blockIdx.x*256 + threadIdx.x;
    float v = (g*4 < NTOK) ? 0.f : 1.f;
    float4* p = (float4*)(out + OFF_WC);
    p[g] = make_float4(v, v, v, v);
}

// ---------------- emb split: fp32 -> (hi,lo) bf16 ----------------
__global__ __launch_bounds__(256) void k_esplit(const float* __restrict__ x,
                                                ushort_t* __restrict__ hi,
                                                ushort_t* __restrict__ lo,
                                                long n4)
{
    long g = (long)blockIdx.x*256 + threadIdx.x;
    if (g >= n4) return;
    float4 v = ((const float4*)x)[g];
    ushort_t h0 = f2bf(v.x), h1 = f2bf(v.y), h2 = f2bf(v.z), h3 = f2bf(v.w);
    ushort4 h = make_ushort4(h0, h1, h2, h3);
    ushort4 l = make_ushort4(f2bf(v.x - bf2f(h0)), f2bf(v.y - bf2f(h1)),
                             f2bf(v.z - bf2f(h2)), f2bf(v.w - bf2f(h3)));
    ((ushort4*)hi)[g] = h;
    ((ushort4*)lo)[g] = l;
}

// ---------------- weight transpose + split ----------------
__global__ __launch_bounds__(256) void k_wsplit(const float* __restrict__ W,
                                                ushort_t* __restrict__ Wt_hi,
                                                ushort_t* __restrict__ Wt_lo,
                                                int K, int N)
{
    __shared__ float t[32][33];
    int k0 = blockIdx.y*32, n0 = blockIdx.x*32;
    int tx = threadIdx.x & 31, ty = threadIdx.x >> 5;
    #pragma unroll
    for (int r = 0; r < 4; ++r)
        t[ty + r*8][tx] = W[(size_t)(k0 + ty + r*8)*N + n0 + tx];
    __syncthreads();
    #pragma unroll
    for (int r = 0; r < 4; ++r) {
        int n = ty + r*8;
        float x = t[tx][n];
        ushort_t h = f2bf(x);
        Wt_hi[(size_t)(n0+n)*K + k0 + tx] = h;
        Wt_lo[(size_t)(n0+n)*K + k0 + tx] = f2bf(x - bf2f(h));
    }
}

// ================= 256x256 8-wave split-bf16 GEMM + tanh, 32x32x16 MFMA ==========
// C = tanh((A_hi+A_lo)[M,1024] @ (B_hi+B_lo)^T), Bt [N][1024]. K=1024. BK=32.
// A_lo = A_hi + aDelta; Bt_lo = Bt_hi + bDelta. 512 threads = 8 waves (2M x 4N),
// per-wave 128x64 output. LDS 128 KiB (2 full bufs), 1 barrier per K-tile.
__global__ __launch_bounds__(512, 2) void k_gemm_mfma256(
    const ushort_t* __restrict__ A_hi, const ushort_t* __restrict__ Bt_hi,
    ushort_t* __restrict__ C_hi, ushort_t* __restrict__ C_lo,
    unsigned aDelta, unsigned bDelta, int N)
{
    __shared__ ushort_t lds[65536];   // 2 x { Ah[256][32] Al Bh Bl } (8192 elems each)

    const int tid  = threadIdx.x;
    const int wave = tid >> 6, lane = tid & 63;
    const int wr = wave >> 2, wc = wave & 3;
    const int l31 = lane & 31, lk = lane >> 5;

    // T1: bijective XCD swizzle (nwg % 8 == 0 for all uses here)
    int nwg = gridDim.x;
    int id = blockIdx.x;
    if (!(nwg & 7)) { int cpx = nwg >> 3; id = (id & 7)*cpx + (id >> 3); }
    const int nx = N >> 8;
    const int n0 = (id % nx) * 256;
    const int m0 = (id / nx) * 256;

    // staging: thread t covers rows (t>>2) and (t>>2)+128, k-slot t&3, pre-swizzled source
    const int srow0 = tid >> 2;
    const int qx = (tid & 3) ^ ((srow0 >> 1) & 3);

    const unsigned offA0 = (unsigned)(m0 + srow0) * 1024u + (unsigned)qx * 8u;
    const unsigned offB0 = (unsigned)(n0 + srow0) * 1024u + (unsigned)qx * 8u;
    const ushort_t* pA0  = A_hi + offA0;
    const ushort_t* pA1  = pA0 + 131072u;          // +128 rows
    const ushort_t* pA0l = pA0 + aDelta;
    const ushort_t* pA1l = pA1 + aDelta;
    const ushort_t* pB0  = Bt_hi + offB0;
    const ushort_t* pB1  = pB0 + 131072u;
    const ushort_t* pB0l = pB0 + bDelta;
    const ushort_t* pB1l = pB1 + bDelta;
    const unsigned ldsS0 = (unsigned)wave * 512u;
    const unsigned ldsS1 = ldsS0 + 4096u;

    // fragment read bases: lane holds row l31, k = lk*8.. within a 16-k half.
    // stored slot = global slot ^ ((row>>1)&3); row's low bits come from l31.
    const int xr = (lane >> 1) & 3;
    const unsigned fb0 = (unsigned)l31*32u + (unsigned)((lk       ^ xr) * 8);  // khalf 0
    const unsigned fb1 = (unsigned)l31*32u + (unsigned)(((2 | lk) ^ xr) * 8);  // khalf 1
    const unsigned wrOff = (unsigned)wr * 4096u;
    const unsigned wcOff = 16384u + (unsigned)wc * 2048u;

    const ushort_t* b00 = lds + fb0;          // buf0, khalf0
    const ushort_t* b01 = lds + fb1;          // buf0, khalf1
    const ushort_t* b10 = b00 + 32768u;       // buf1
    const ushort_t* b11 = b01 + 32768u;

    f32x16 acc[4][2] = {};

#define STG(KT, WB) { \
    unsigned wb_ = (unsigned)(WB) * 32768u; \
    gload16(pA0  + (KT), lds + wb_ +           ldsS0); \
    gload16(pA1  + (KT), lds + wb_ +           ldsS1); \
    gload16(pA0l + (KT), lds + wb_ +  8192u +  ldsS0); \
    gload16(pA1l + (KT), lds + wb_ +  8192u +  ldsS1); \
    gload16(pB0  + (KT), lds + wb_ + 16384u +  ldsS0); \
    gload16(pB1  + (KT), lds + wb_ + 16384u +  ldsS1); \
    gload16(pB0l + (KT), lds + wb_ + 24576u +  ldsS0); \
    gload16(pB1l + (KT), lds + wb_ + 24576u +  ldsS1); \
}

// base pointer already includes buf + khalf(fb) per lane; rest is compile-time imm
#define RA(B, hl, i) (*(const short8v*)((B) + (hl)*8192u + wrOff + (unsigned)(i)*1024u))
#define RB(B, hl, j) (*(const short8v*)((B) + wcOff + (hl)*8192u + (unsigned)(j)*1024u))

#define MM(A8, B8, C16) __builtin_amdgcn_mfma_f32_32x32x16_bf16(A8, B8, C16, 0, 0, 0)

    // prologue: stage tile 0 into buf 0
    STG(0, 0);
    __syncthreads();

    #pragma unroll 1
    for (int kt = 0; kt < 1024; kt += 32) {
        const int par = (kt >> 5) & 1;
        const ushort_t* c0 = par ? b10 : b00;   // current buf, khalf0
        const ushort_t* c1 = par ? b11 : b01;   // current buf, khalf1

        if (kt + 32 < 1024) STG(kt + 32, par ^ 1);

        // B fragments for the whole tile (8 reads)
        short8v B0h0 = RB(c0,0,0), B0l0 = RB(c0,1,0);
        short8v B0h1 = RB(c1,0,0), B0l1 = RB(c1,1,0);
        short8v B1h0 = RB(c0,0,1), B1l0 = RB(c0,1,1);
        short8v B1h1 = RB(c1,0,1), B1l1 = RB(c1,1,1);

        __builtin_amdgcn_s_setprio(1);
        #pragma unroll
        for (int i = 0; i < 4; ++i) {
            short8v Ah0 = RA(c0,0,i), Al0 = RA(c0,1,i);
            short8v Ah1 = RA(c1,0,i), Al1 = RA(c1,1,i);
            acc[i][0] = MM(Ah0, B0h0, acc[i][0]);
            acc[i][1] = MM(Ah0, B1h0, acc[i][1]);
            acc[i][0] = MM(Ah0, B0l0, acc[i][0]);
            acc[i][1] = MM(Ah0, B1l0, acc[i][1]);
            acc[i][0] = MM(Al0, B0h0, acc[i][0]);
            acc[i][1] = MM(Al0, B1h0, acc[i][1]);
            acc[i][0] = MM(Ah1, B0h1, acc[i][0]);
            acc[i][1] = MM(Ah1, B1h1, acc[i][1]);
            acc[i][0] = MM(Ah1, B0l1, acc[i][0]);
            acc[i][1] = MM(Ah1, B1l1, acc[i][1]);
            acc[i][0] = MM(Al1, B0h1, acc[i][0]);
            acc[i][1] = MM(Al1, B1h1, acc[i][1]);
        }
        __builtin_amdgcn_s_setprio(0);

        // single boundary barrier: drains staging + read/write separation
        __syncthreads();
    }

    // epilogue: 32x32 C/D layout col = lane&31, row = (reg&3)+8*(reg>>2)+4*(lane>>5)
    #pragma unroll
    for (int i = 0; i < 4; ++i)
        #pragma unroll
        for (int j = 0; j < 2; ++j)
            #pragma unroll
            for (int r = 0; r < 16; ++r) {
                int row = m0 + wr*128 + i*32 + (r & 3) + 8*(r >> 2) + 4*lk;
                int col = n0 + wc*64 + j*32 + l31;
                float t = tanhf(acc[i][j][r]);
                size_t idx = (size_t)row*N + col;
                ushort_t h = f2bf(t);
                C_hi[idx] = h;
                C_lo[idx] = f2bf(t - bf2f(h));
            }
#undef STG
#undef RA
#undef RB
#undef MM
}

// ---------------- 128x128 split-bf16 MFMA GEMM + tanh (layer 3 / fallback) ----------------
__global__ __launch_bounds__(256, 2) void k_gemm_mfma(
    const ushort_t* __restrict__ A_hi, const ushort_t* __restrict__ A_lo,
    const ushort_t* __restrict__ Bt_hi, const ushort_t* __restrict__ Bt_lo,
    ushort_t* __restrict__ C_hi, ushort_t* __restrict__ C_lo,
    float* __restrict__ Cf,
    int N)
{
    const int K = 1024;
    __shared__ ushort_t lds[16384];

    const int tid  = threadIdx.x;
    const int wave = tid >> 6, lane = tid & 63;
    const int wr = wave >> 1, wc = wave & 1;

    int nwg = gridDim.x * gridDim.y;
    int id = blockIdx.y * gridDim.x + blockIdx.x;
    if (!(nwg & 7)) { int cpx = nwg >> 3; id = (id & 7)*cpx + (id >> 3); }
    const int m0 = (id / gridDim.x) * 128, n0 = (id % gridDim.x) * 128;

    f32x4 acc[4][4] = {};

    int srow[2], sq[2], slbase[2];
    #pragma unroll
    for (int r = 0; r < 2; ++r) {
        int row = wave*32 + r*16 + (lane >> 2);
        srow[r]   = row;
        sq[r]     = (lane & 3) ^ ((row >> 1) & 3);
        slbase[r] = wave*1024 + r*512;
    }

    const int fr = lane & 15, fq = lane >> 4;

    for (int kt = 0; kt < K; kt += 32) {
        __syncthreads();
        #pragma unroll
        for (int r = 0; r < 2; ++r) {
            size_t ga = (size_t)(m0 + srow[r]) * K + kt + sq[r]*8;
            size_t gb = (size_t)(n0 + srow[r]) * K + kt + sq[r]*8;
            gload16(A_hi  + ga, lds          + slbase[r]);
            gload16(A_lo  + ga, lds + 4096   + slbase[r]);
            gload16(Bt_hi + gb, lds + 8192   + slbase[r]);
            gload16(Bt_lo + gb, lds + 12288  + slbase[r]);
        }
        __syncthreads();

        short8v ah[4], al[4], bh[4], bl[4];
        #pragma unroll
        for (int i = 0; i < 4; ++i) {
            int rowa = wr*64 + i*16 + fr;
            int offa = rowa*32 + ((fq ^ ((rowa >> 1) & 3)) * 8);
            ah[i] = *(const short8v*)(lds + offa);
            al[i] = *(const short8v*)(lds + 4096 + offa);
            int rowb = wc*64 + i*16 + fr;
            int offb = rowb*32 + ((fq ^ ((rowb >> 1) & 3)) * 8);
            bh[i] = *(const short8v*)(lds + 8192 + offb);
            bl[i] = *(const short8v*)(lds + 12288 + offb);
        }
        #pragma unroll
        for (int i = 0; i < 4; ++i)
            #pragma unroll
            for (int j = 0; j < 4; ++j) {
                acc[i][j] = __builtin_amdgcn_mfma_f32_16x16x32_bf16(ah[i], bh[j], acc[i][j], 0, 0, 0);
                acc[i][j] = __builtin_amdgcn_mfma_f32_16x16x32_bf16(ah[i], bl[j], acc[i][j], 0, 0, 0);
                acc[i][j] = __builtin_amdgcn_mfma_f32_16x16x32_bf16(al[i], bh[j], acc[i][j], 0, 0, 0);
            }
    }

    #pragma unroll
    for (int i = 0; i < 4; ++i)
        #pragma unroll
        for (int j = 0; j < 4; ++j)
            #pragma unroll
            for (int r = 0; r < 4; ++r) {
                int row = m0 + wr*64 + i*16 + fq*4 + r;
                int col = n0 + wc*64 + j*16 + fr;
                float t = tanhf(acc[i][j][r]);
                size_t idx = (size_t)row*N + col;
                if (Cf) Cf[idx] = t;
                if (C_hi) {
                    ushort_t h = f2bf(t);
                    C_hi[idx] = h;
                    C_lo[idx] = f2bf(t - bf2f(h));
                }
            }
}

// ---------------- MFMA assignment: argmin_c (c2[c] - 2 * se.cent) ----------------
__global__ __launch_bounds__(256) void k_assign_mfma(
    const ushort_t* __restrict__ SEh, const ushort_t* __restrict__ SEl,
    const ushort_t* __restrict__ ch, const ushort_t* __restrict__ cl,
    const float* __restrict__ c2,
    int* __restrict__ sc, float* __restrict__ out_w)
{
    __shared__ ushort_t lds[16384];
    __shared__ float c2s[512];
    __shared__ float redD[128][2];
    __shared__ int   redI[128][2];

    const int modal = blockIdx.y;
    const int t0 = blockIdx.x * 128;
    const int tid  = threadIdx.x;
    const int wave = tid >> 6, lane = tid & 63;
    const int wr = wave >> 1, wc = wave & 1;
    const int fr = lane & 15, fq = lane >> 4;

    const ushort_t* seh = SEh + (size_t)modal * NTOK * 256;
    const ushort_t* sel = SEl + (size_t)modal * NTOK * 256;

    c2s[tid] = c2[tid];
    c2s[tid + 256] = c2[tid + 256];

    int srow[2], sq[2], slbase[2];
    #pragma unroll
    for (int r = 0; r < 2; ++r) {
        int row = wave*32 + r*16 + (lane >> 2);
        srow[r]   = row;
        sq[r]     = (lane & 3) ^ ((row >> 1) & 3);
        slbase[r] = wave*1024 + r*512;
    }

    float bd[16]; int bi[16];
    #pragma unroll
    for (int s = 0; s < 16; ++s) { bd[s] = 3.4e38f; bi[s] = 0; }

    for (int j = 0; j < 4; ++j) {
        f32x4 acc[4][4] = {};
        for (int kt = 0; kt < 256; kt += 32) {
            __syncthreads();
            #pragma unroll
            for (int r = 0; r < 2; ++r) {
                size_t ga = (size_t)(t0 + srow[r]) * 256 + kt + sq[r]*8;
                size_t gc = (size_t)(j*128 + srow[r]) * 256 + kt + sq[r]*8;
                gload16(seh + ga, lds          + slbase[r]);
                gload16(sel + ga, lds + 4096   + slbase[r]);
                gload16(ch  + gc, lds + 8192   + slbase[r]);
                gload16(cl  + gc, lds + 12288  + slbase[r]);
            }
            __syncthreads();

            short8v ah[4], al[4], bh[4], bl[4];
            #pragma unroll
            for (int i = 0; i < 4; ++i) {
                int rowa = wr*64 + i*16 + fr;
                int offa = rowa*32 + ((fq ^ ((rowa >> 1) & 3)) * 8);
                ah[i] = *(const short8v*)(lds + offa);
                al[i] = *(const short8v*)(lds + 4096 + offa);
                int rowb = wc*64 + i*16 + fr;
                int offb = rowb*32 + ((fq ^ ((rowb >> 1) & 3)) * 8);
                bh[i] = *(const short8v*)(lds + 8192 + offb);
                bl[i] = *(const short8v*)(lds + 12288 + offb);
            }
            #pragma unroll
            for (int i = 0; i < 4; ++i)
                #pragma unroll
                for (int jj = 0; jj < 4; ++jj) {
                    acc[i][jj] = __builtin_amdgcn_mfma_f32_16x16x32_bf16(ah[i], bh[jj], acc[i][jj], 0, 0, 0);
                    acc[i][jj] = __builtin_amdgcn_mfma_f32_16x16x32_bf16(ah[i], bl[jj], acc[i][jj], 0, 0, 0);
                    acc[i][jj] = __builtin_amdgcn_mfma_f32_16x16x32_bf16(al[i], bh[jj], acc[i][jj], 0, 0, 0);
                }
        }
        #pragma unroll
        for (int i = 0; i < 4; ++i)
            #pragma unroll
            for (int jj = 0; jj < 4; ++jj) {
                int col = j*128 + wc*64 + jj*16 + fr;
                float cc = c2s[col];
                #pragma unroll
                for (int r = 0; r < 4; ++r) {
                    float d = cc - 2.f * acc[i][jj][r];
                    int s = i*4 + r;
                    if (d < bd[s]) { bd[s] = d; bi[s] = col; }
                }
            }
    }

    #pragma unroll
    for (int s = 0; s < 16; ++s) {
        #pragma unroll
        for (int off = 1; off < 16; off <<= 1) {
            float od = __shfl_xor(bd[s], off);
            int   oi = __shfl_xor(bi[s], off);
            if (od < bd[s] || (od == bd[s] && oi < bi[s])) { bd[s] = od; bi[s] = oi; }
        }
    }
    if (fr == 0) {
        #pragma unroll
        for (int i = 0; i < 4; ++i)
            #pragma unroll
            for (int r = 0; r < 4; ++r) {
                int tl = wr*64 + i*16 + fq*4 + r;
                redD[tl][wc] = bd[i*4 + r];
                redI[tl][wc] = bi[i*4 + r];
            }
    }
    __syncthreads();
    if (tid < 128) {
        float d0 = redD[tid][0], d1 = redD[tid][1];
        int   i0 = redI[tid][0], i1 = redI[tid][1];
        if (d1 < d0 || (d1 == d0 && i1 < i0)) { d0 = d1; i0 = i1; }
        int g = t0 + tid;
        sc[modal*NTOK + g] = i0;
        out_w[OFF_SC + (size_t)modal*NTOK + g] = (float)i0;
    }
}

// ---------------- fp32 fallback assignment ----------------
__global__ __launch_bounds__(256) void k_assign(
    const float* __restrict__ out_ro,
    const float* __restrict__ c2,
    int* __restrict__ sc,
    float* __restrict__ out_w)
{
    const int modal = blockIdx.y;
    const int tok0 = blockIdx.x * 64;
    const float* se   = out_ro + OFF_SE + (size_t)modal * NTOK * 256;
    const float* cent = out_ro + OFF_CENT;

    __shared__ float4 se4[64][64];
    __shared__ float4 ct4[64][64];

    const int tid = threadIdx.x;
    const int tt = tid & 15, cc = tid >> 4;

    {
        int rbase = tid >> 6;
        int d4 = tid & 63;
        #pragma unroll
        for (int i = 0; i < 16; ++i) {
            int t = i*4 + rbase;
            float4 v = *(const float4*)(se + (size_t)(tok0 + t)*256 + d4*4);
            se4[t][d4 ^ (t >> 2)] = v;
        }
    }
    __syncthreads();

    float e2r[4];
    #pragma unroll
    for (int k2 = 0; k2 < 4; ++k2) {
        float s = 0.f;
        for (int d4 = 0; d4 < 64; ++d4) {
            float4 v = se4[4*tt + k2][d4 ^ tt];
            s += dot4(v, v);
        }
        e2r[k2] = s;
    }

    float bd[4]; int bi[4];
    #pragma unroll
    for (int k2 = 0; k2 < 4; ++k2) { bd[k2] = 3.4e38f; bi[k2] = 0; }

    for (int ctile = 0; ctile < 8; ++ctile) {
        int c0 = ctile * 64;
        {
            int rbase = tid >> 6;
            int d4 = tid & 63;
            #pragma unroll
            for (int i = 0; i < 16; ++i) {
                int r = i*4 + rbase;
                float4 v = *(const float4*)(cent + (size_t)(c0 + r)*256 + d4*4);
                ct4[r][d4 ^ (r >> 2)] = v;
            }
        }
        __syncthreads();

        float accd[4][4];
        #pragma unroll
        for (int a = 0; a < 4; ++a)
            #pragma unroll
            for (int b = 0; b < 4; ++b) accd[a][b] = 0.f;

        for (int d4 = 0; d4 < 64; ++d4) {
            float4 sv[4], cv[4];
            #pragma unroll
            for (int k2 = 0; k2 < 4; ++k2) sv[k2] = se4[4*tt + k2][d4 ^ tt];
            #pragma unroll
            for (int jx = 0; jx < 4; ++jx) cv[jx] = ct4[4*cc + jx][d4 ^ cc];
            #pragma unroll
            for (int k2 = 0; k2 < 4; ++k2)
                #pragma unroll
                for (int jx = 0; jx < 4; ++jx)
                    accd[k2][jx] += dot4(sv[k2], cv[jx]);
        }

        #pragma unroll
        for (int jx = 0; jx < 4; ++jx) {
            int cidx = c0 + 4*cc + jx;
            float cj = c2[cidx];
            #pragma unroll
            for (int k2 = 0; k2 < 4; ++k2) {
                float d = cj + e2r[k2] - 2.f * accd[k2][jx];
                if (d < bd[k2]) { bd[k2] = d; bi[k2] = cidx; }
            }
        }
        __syncthreads();
    }

    float* red_d = (float*)ct4;
    int*   red_i = (int*)ct4 + 64*17;
    #pragma unroll
    for (int k2 = 0; k2 < 4; ++k2) {
        red_d[(4*tt + k2)*17 + cc] = bd[k2];
        red_i[(4*tt + k2)*17 + cc] = bi[k2];
    }
    __syncthreads();
    if (tid < 64) {
        float b = red_d[tid*17]; int ix = red_i[tid*17];
        #pragma unroll
        for (int q = 1; q < 16; ++q) {
            float d = red_d[tid*17 + q]; int i2 = red_i[tid*17 + q];
            if (d < b || (d == b && i2 < ix)) { b = d; ix = i2; }
        }
        int g = tok0 + tid;
        sc[modal*NTOK + g] = ix;
        out_w[OFF_SC + (size_t)modal*NTOK + g] = (float)ix;
    }
}

// ---------------- stable counting sort ----------------
__global__ __launch_bounds__(256) void k_hist(const int* __restrict__ sc,
                                              int* __restrict__ blockHist)
{
    int modal = blockIdx.y, blk = blockIdx.x, tid = threadIdx.x;
    __shared__ int h[512];
    h[tid] = 0; h[tid + 256] = 0;
    __syncthreads();
    atomicAdd(&h[sc[modal*NTOK + blk*256 + tid]], 1);
    __syncthreads();
    int base = (modal*128 + blk) * 512;
    blockHist[base + tid]       = h[tid];
    blockHist[base + tid + 256] = h[tid + 256];
}

__global__ __launch_bounds__(512) void k_scan(const int* __restrict__ blockHist,
                                              int* __restrict__ blockBase,
                                              int* __restrict__ classBase,
                                              float* __restrict__ out)
{
    int modal = blockIdx.x;
    int c = threadIdx.x;
    int run = 0;
    for (int b = 0; b < 128; ++b) {
        int idx = (modal*128 + b)*512 + c;
        blockBase[idx] = run;
        run += blockHist[idx];
    }
    float* cnt = out + (modal ? OFF_CI : OFF_CT);
    cnt[c] = (float)run;

    __shared__ int s[512];
    s[c] = run;
    __syncthreads();
    int total = run;
    for (int off = 1; off < 512; off <<= 1) {
        int v = 0;
        if (c >= off) v = s[c - off];
        __syncthreads();
        s[c] += v;
        __syncthreads();
    }
    classBase[modal*512 + c] = s[c] - total;
}

__global__ __launch_bounds__(256) void k_scatter(const int* __restrict__ sc,
                                                 const int* __restrict__ blockBase,
                                                 const int* __restrict__ classBase,
                                                 float* __restrict__ out)
{
    int modal = blockIdx.y, blk = blockIdx.x, tid = threadIdx.x;
    __shared__ int cls[256];
    int t = blk*256 + tid;
    int c = sc[modal*NTOK + t];
    cls[tid] = c;
    __syncthreads();
    int rank = 0;
    for (int j = 0; j < tid; ++j) rank += (cls[j] == c) ? 1 : 0;
    int pos = classBase[modal*512 + c] + blockBase[(modal*128 + blk)*512 + c] + rank;
    float* oo = out + (modal ? OFF_OI : OFF_OT);
    oo[pos] = (float)t;
}

extern "C" void kernel_launch(void* const* d_in, const int* in_sizes, int n_in,
                              void* d_out, int out_size, void* d_ws, size_t ws_size,
                              hipStream_t stream)
{
    const float* text_emb  = (const float*)d_in[0];
    const float* image_emb = (const float*)d_in[1];
    const float* W[2][3] = {
        {(const float*)d_in[2], (const float*)d_in[3], (const float*)d_in[4]},
        {(const float*)d_in[5], (const float*)d_in[6], (const float*)d_in[7]}
    };
    const float* cent_raw = (const float*)d_in[8];
    float* out = (float*)d_out;
    char* w = (char*)d_ws;

    int*   sc        = (int*)w;
    int*   blockHist = (int*)(w + 0x40000);
    int*   blockBase = (int*)(w + 0xC0000);
    int*   classBase = (int*)(w + 0x140000);
    float* c2        = (float*)(w + 0x141000);
    ushort_t* cent_h = (ushort_t*)(w + 0x142000);
    ushort_t* cent_l = (ushort_t*)(w + 0x182000);

    ushort_t* wreg = (ushort_t*)(w + 0x200000);
    const size_t WM = 4*1048576 + 2*262144;

    ushort_t* SEh = (ushort_t*)(w + 0x1400000);
    ushort_t* SEl = (ushort_t*)(w + 0x3400000);

    bool mfmaAssign = true;
    size_t actoff = 0x5400000;
    int Mc = 0;
    for (int c = NTOK; c >= 128; c >>= 1)
        if (actoff + (size_t)c*8192 <= ws_size) { Mc = c; break; }
    if (Mc == 0) {
        mfmaAssign = false;
        actoff = 0x1400000;
        for (int c = NTOK; c >= 128; c >>= 1)
            if (actoff + (size_t)c*8192 <= ws_size) { Mc = c; break; }
        if (Mc == 0) Mc = 128;
    }
    ushort_t* act = (ushort_t*)(w + actoff);
    const bool big = (Mc % 256 == 0);

    k_cent<<<dim3(512), dim3(64), 0, stream>>>(cent_raw, out, c2, cent_h, cent_l);
    k_wc  <<<dim3(64),  dim3(256), 0, stream>>>(out);

    for (int m = 0; m < 2; ++m) {
        const float* emb = m ? image_emb : text_emb;
        ushort_t* w1h = wreg + (size_t)m*WM;
        ushort_t* w1l = w1h + 1048576;
        ushort_t* w2h = w1l + 1048576;
        ushort_t* w2l = w2h + 1048576;
        ushort_t* w3h = w2l + 1048576;
        ushort_t* w3l = w3h + 262144;

        k_wsplit<<<dim3(32, 32), dim3(256), 0, stream>>>(W[m][0], w1h, w1l, 1024, 1024);
        k_wsplit<<<dim3(32, 32), dim3(256), 0, stream>>>(W[m][1], w2h, w2l, 1024, 1024);
        k_wsplit<<<dim3(8,  32), dim3(256), 0, stream>>>(W[m][2], w3h, w3l, 1024, 256);

        ushort_t* Ah = act;
        ushort_t* Al = Ah + (size_t)Mc*1024;
        ushort_t* Hh = Al + (size_t)Mc*1024;
        ushort_t* Hl = Hh + (size_t)Mc*1024;

        for (int s0 = 0; s0 < NTOK; s0 += Mc) {
            long n4 = (long)Mc*1024/4;
            k_esplit<<<dim3((unsigned)((n4 + 255)/256)), dim3(256), 0, stream>>>(
                emb + (size_t)s0*1024, Ah, Al, n4);
            if (big) {
                k_gemm_mfma256<<<dim3((Mc/256)*4), dim3(512), 0, stream>>>(
                    Ah, w1h, Hh, Hl, (unsigned)Mc*1024u, 1048576u, 1024);
                k_gemm_mfma256<<<dim3((Mc/256)*4), dim3(512), 0, stream>>>(
                    Hh, w2h, Ah, Al, (unsigned)Mc*1024u, 1048576u, 1024);
            } else {
                k_gemm_mfma<<<dim3(8, Mc/128), dim3(256), 0, stream>>>(
                    Ah, Al, w1h, w1l, Hh, Hl, nullptr, 1024);
                k_gemm_mfma<<<dim3(8, Mc/128), dim3(256), 0, stream>>>(
                    Hh, Hl, w2h, w2l, Ah, Al, nullptr, 1024);
            }
            ushort_t* seh_ptr = mfmaAssign ? SEh + ((size_t)m*NTOK + s0)*256 : nullptr;
            ushort_t* sel_ptr = mfmaAssign ? SEl + ((size_t)m*NTOK + s0)*256 : nullptr;
            k_gemm_mfma<<<dim3(2, Mc/128), dim3(256), 0, stream>>>(
                Ah, Al, w3h, w3l, seh_ptr, sel_ptr,
                out + OFF_SE + ((size_t)m*NTOK + s0)*256, 256);
        }
    }

    if (mfmaAssign) {
        k_assign_mfma<<<dim3(256, 2), dim3(256), 0, stream>>>(
            SEh, SEl, cent_h, cent_l, c2, sc, out);
    } else {
        k_assign<<<dim3(512, 2), dim3(256), 0, stream>>>(out, c2, sc, out);
    }
    k_hist   <<<dim3(128, 2), dim3(256), 0, stream>>>(sc, blockHist);
    k_scan   <<<dim3(2),      dim3(512), 0, stream>>>(blockHist, blockBase, classBase, out);
    k_scatter<<<dim3(128, 2), dim3(256), 0, stream>>>(sc, blockBase, classBase, out);
}

// Round 7
// 1088.436 us; speedup vs baseline: 1.0635x; 1.0635x over previous
//
#include <hip/hip_runtime.h>
#include <math.h>

#define NTOK 32768
typedef unsigned short ushort_t;

// d_out offsets (in floats)
#define OFF_CENT 0
#define OFF_SE   131072
#define OFF_WC   16908288
#define OFF_SC   16973824
#define OFF_OT   17039360
#define OFF_CT   17072128
#define OFF_OI   17072640
#define OFF_CI   17105408

typedef __attribute__((ext_vector_type(8))) short short8v;
typedef __attribute__((ext_vector_type(4))) float f32x4;

__device__ __forceinline__ float dot4(float4 a, float4 b){
    return a.x*b.x + a.y*b.y + a.z*b.z + a.w*b.w;
}

// RNE float -> bf16 bits
__device__ __forceinline__ ushort_t f2bf(float x){
    unsigned int u = __float_as_uint(x);
    unsigned int r = (u + 0x7fffu + ((u >> 16) & 1u)) >> 16;
    return (ushort_t)r;
}
__device__ __forceinline__ float bf2f(ushort_t h){
    return __uint_as_float(((unsigned int)h) << 16);
}

__device__ __forceinline__ void gload16(const void* g, void* l){
    __builtin_amdgcn_global_load_lds(
        (const __attribute__((address_space(1))) void*)g,
        (__attribute__((address_space(3))) void*)l,
        16, 0, 0);
}

// ---------------- centroids: tanh + c2 + hi/lo split ----------------
__global__ __launch_bounds__(64) void k_cent(const float* __restrict__ raw,
                                             float* __restrict__ out,
                                             float* __restrict__ c2,
                                             ushort_t* __restrict__ ch,
                                             ushort_t* __restrict__ cl)
{
    int c = blockIdx.x, l = threadIdx.x;
    float4 v = *(const float4*)(raw + (size_t)c*256 + l*4);
    float4 t;
    t.x = tanhf(v.x); t.y = tanhf(v.y); t.z = tanhf(v.z); t.w = tanhf(v.w);
    *(float4*)(out + OFF_CENT + (size_t)c*256 + l*4) = t;
    ushort4 h = make_ushort4(f2bf(t.x), f2bf(t.y), f2bf(t.z), f2bf(t.w));
    ushort4 lo = make_ushort4(f2bf(t.x - bf2f(h.x)), f2bf(t.y - bf2f(h.y)),
                              f2bf(t.z - bf2f(h.z)), f2bf(t.w - bf2f(h.w)));
    *(ushort4*)(ch + (size_t)c*256 + l*4) = h;
    *(ushort4*)(cl + (size_t)c*256 + l*4) = lo;
    float s = dot4(t, t);
    #pragma unroll
    for (int off = 32; off > 0; off >>= 1) s += __shfl_down(s, off);
    if (l == 0) c2[c] = s;
}

// ---------------- word_class fill ----------------
__global__ __launch_bounds__(256) void k_wc(float* __restrict__ out)
{
    int g = blockIdx.x*256 + threadIdx.x;
    float v = (g*4 < NTOK) ? 0.f : 1.f;
    float4* p = (float4*)(out + OFF_WC);
    p[g] = make_float4(v, v, v, v);
}

// ---------------- emb split: fp32 -> (hi,lo) bf16 ----------------
__global__ __launch_bounds__(256) void k_esplit(const float* __restrict__ x,
                                                ushort_t* __restrict__ hi,
                                                ushort_t* __restrict__ lo,
                                                long n4)
{
    long g = (long)blockIdx.x*256 + threadIdx.x;
    if (g >= n4) return;
    float4 v = ((const float4*)x)[g];
    ushort_t h0 = f2bf(v.x), h1 = f2bf(v.y), h2 = f2bf(v.z), h3 = f2bf(v.w);
    ushort4 h = make_ushort4(h0, h1, h2, h3);
    ushort4 l = make_ushort4(f2bf(v.x - bf2f(h0)), f2bf(v.y - bf2f(h1)),
                             f2bf(v.z - bf2f(h2)), f2bf(v.w - bf2f(h3)));
    ((ushort4*)hi)[g] = h;
    ((ushort4*)lo)[g] = l;
}

// ---------------- weight transpose + split ----------------
__global__ __launch_bounds__(256) void k_wsplit(const float* __restrict__ W,
                                                ushort_t* __restrict__ Wt_hi,
                                                ushort_t* __restrict__ Wt_lo,
                                                int K, int N)
{
    __shared__ float t[32][33];
    int k0 = blockIdx.y*32, n0 = blockIdx.x*32;
    int tx = threadIdx.x & 31, ty = threadIdx.x >> 5;
    #pragma unroll
    for (int r = 0; r < 4; ++r)
        t[ty + r*8][tx] = W[(size_t)(k0 + ty + r*8)*N + n0 + tx];
    __syncthreads();
    #pragma unroll
    for (int r = 0; r < 4; ++r) {
        int n = ty + r*8;
        float x = t[tx][n];
        ushort_t h = f2bf(x);
        Wt_hi[(size_t)(n0+n)*K + k0 + tx] = h;
        Wt_lo[(size_t)(n0+n)*K + k0 + tx] = f2bf(x - bf2f(h));
    }
}

// ================= 256x256 8-wave split-bf16 GEMM + tanh, 16x16x32 MFMA ==========
// C = tanh((A_hi+A_lo)[M,1024] @ (B_hi+B_lo)^T), Bt [N][1024]. K=1024. BK=32.
// A_lo = A_hi + aDelta; Bt_lo = Bt_hi + bDelta. 512 threads = 8 waves (2M x 4N),
// per-wave 128x64 output. LDS 128 KiB (2 full bufs), 1 barrier per K-tile.
__global__ __launch_bounds__(512, 2) void k_gemm_mfma256(
    const ushort_t* __restrict__ A_hi, const ushort_t* __restrict__ Bt_hi,
    ushort_t* __restrict__ C_hi, ushort_t* __restrict__ C_lo,
    unsigned aDelta, unsigned bDelta, int N)
{
    __shared__ ushort_t lds[65536];   // 2 x { Ah[256][32] Al Bh Bl } (8192 elems each)

    const int tid  = threadIdx.x;
    const int wave = tid >> 6, lane = tid & 63;
    const int wr = wave >> 2, wc = wave & 3;
    const int fr = lane & 15, fq = lane >> 4;

    // T1: bijective XCD swizzle (nwg % 8 == 0 for all uses here)
    int nwg = gridDim.x;
    int id = blockIdx.x;
    if (!(nwg & 7)) { int cpx = nwg >> 3; id = (id & 7)*cpx + (id >> 3); }
    const int nx = N >> 8;
    const int n0 = (id % nx) * 256;
    const int m0 = (id / nx) * 256;

    // staging: thread t covers rows (t>>2) and (t>>2)+128, k-slot t&3, pre-swizzled source
    const int srow0 = tid >> 2;
    const int qx = (tid & 3) ^ ((srow0 >> 1) & 3);

    const unsigned offA0 = (unsigned)(m0 + srow0) * 1024u + (unsigned)qx * 8u;
    const unsigned offB0 = (unsigned)(n0 + srow0) * 1024u + (unsigned)qx * 8u;
    const ushort_t* pA0  = A_hi + offA0;
    const ushort_t* pA1  = pA0 + 131072u;          // +128 rows
    const ushort_t* pA0l = pA0 + aDelta;
    const ushort_t* pA1l = pA1 + aDelta;
    const ushort_t* pB0  = Bt_hi + offB0;
    const ushort_t* pB1  = pB0 + 131072u;
    const ushort_t* pB0l = pB0 + bDelta;
    const ushort_t* pB1l = pB1 + bDelta;
    const unsigned ldsS0 = (unsigned)wave * 512u;
    const unsigned ldsS1 = ldsS0 + 4096u;

    // fragment read base: row fr, k-group fq; stored slot = fq ^ ((fr>>1)&3) (lane-only,
    // conflict-free: each 8-lane group covers the full 128B bank period)
    const unsigned fb = (unsigned)fr*32u + (unsigned)((fq ^ ((fr >> 1) & 3)) * 8);
    const ushort_t* p0 = lds + fb;            // buf 0
    const ushort_t* p1 = p0 + 32768u;         // buf 1

    f32x4 acc[8][4] = {};

#define STG(KT, WB) { \
    unsigned wb_ = (unsigned)(WB) * 32768u; \
    gload16(pA0  + (KT), lds + wb_ +           ldsS0); \
    gload16(pA1  + (KT), lds + wb_ +           ldsS1); \
    gload16(pA0l + (KT), lds + wb_ +  8192u +  ldsS0); \
    gload16(pA1l + (KT), lds + wb_ +  8192u +  ldsS1); \
    gload16(pB0  + (KT), lds + wb_ + 16384u +  ldsS0); \
    gload16(pB1  + (KT), lds + wb_ + 16384u +  ldsS1); \
    gload16(pB0l + (KT), lds + wb_ + 24576u +  ldsS0); \
    gload16(pB1l + (KT), lds + wb_ + 24576u +  ldsS1); \
}

// base pointer holds buf + per-lane fb; everything else is a compile-time immediate
#define RA(P, hl, i) (*(const short8v*)((P) + (hl)*8192u + (unsigned)wr*4096u + (unsigned)(i)*512u))
#define RB(P, hl, j) (*(const short8v*)((P) + 16384u + (hl)*8192u + (unsigned)wc*2048u + (unsigned)(j)*512u))

#define MM16(A8, B8, C4) __builtin_amdgcn_mfma_f32_16x16x32_bf16(A8, B8, C4, 0, 0, 0)

    // prologue: stage tile 0 into buf 0
    STG(0, 0);
    __syncthreads();

    #pragma unroll 1
    for (int kt = 0; kt < 1024; kt += 32) {
        const int par = (kt >> 5) & 1;
        const ushort_t* cp = par ? p1 : p0;

        // stage next tile into the other buffer (in flight across this tile's compute)
        if (kt + 32 < 1024) STG(kt + 32, par ^ 1);

        // B fragments for the whole tile (8 reads)
        short8v bh0 = RB(cp,0,0), bl0 = RB(cp,1,0);
        short8v bh1 = RB(cp,0,1), bl1 = RB(cp,1,1);
        short8v bh2 = RB(cp,0,2), bl2 = RB(cp,1,2);
        short8v bh3 = RB(cp,0,3), bl3 = RB(cp,1,3);

        __builtin_amdgcn_s_setprio(1);
        #pragma unroll
        for (int i = 0; i < 8; ++i) {
            short8v ah = RA(cp,0,i), al = RA(cp,1,i);
            // same-acc reuse spaced 4 MFMAs apart
            acc[i][0] = MM16(ah, bh0, acc[i][0]);
            acc[i][1] = MM16(ah, bh1, acc[i][1]);
            acc[i][2] = MM16(ah, bh2, acc[i][2]);
            acc[i][3] = MM16(ah, bh3, acc[i][3]);
            acc[i][0] = MM16(ah, bl0, acc[i][0]);
            acc[i][1] = MM16(ah, bl1, acc[i][1]);
            acc[i][2] = MM16(ah, bl2, acc[i][2]);
            acc[i][3] = MM16(ah, bl3, acc[i][3]);
            acc[i][0] = MM16(al, bh0, acc[i][0]);
            acc[i][1] = MM16(al, bh1, acc[i][1]);
            acc[i][2] = MM16(al, bh2, acc[i][2]);
            acc[i][3] = MM16(al, bh3, acc[i][3]);
        }
        __builtin_amdgcn_s_setprio(0);

        // single boundary barrier: drains staging + read/write separation
        __syncthreads();
    }

    // epilogue: C/D layout col = lane&15, row = (lane>>4)*4 + reg  [m89-verified]
    #pragma unroll
    for (int i = 0; i < 8; ++i)
        #pragma unroll
        for (int j = 0; j < 4; ++j)
            #pragma unroll
            for (int r = 0; r < 4; ++r) {
                int row = m0 + wr*128 + i*16 + fq*4 + r;
                int col = n0 + wc*64 + j*16 + fr;
                float t = tanhf(acc[i][j][r]);
                size_t idx = (size_t)row*N + col;
                ushort_t h = f2bf(t);
                C_hi[idx] = h;
                C_lo[idx] = f2bf(t - bf2f(h));
            }
#undef STG
#undef RA
#undef RB
#undef MM16
}

// ---------------- 128x128 split-bf16 MFMA GEMM + tanh (layer 3 / fallback) ----------------
__global__ __launch_bounds__(256, 2) void k_gemm_mfma(
    const ushort_t* __restrict__ A_hi, const ushort_t* __restrict__ A_lo,
    const ushort_t* __restrict__ Bt_hi, const ushort_t* __restrict__ Bt_lo,
    ushort_t* __restrict__ C_hi, ushort_t* __restrict__ C_lo,
    float* __restrict__ Cf,
    int N)
{
    const int K = 1024;
    __shared__ ushort_t lds[16384];

    const int tid  = threadIdx.x;
    const int wave = tid >> 6, lane = tid & 63;
    const int wr = wave >> 1, wc = wave & 1;

    int nwg = gridDim.x * gridDim.y;
    int id = blockIdx.y * gridDim.x + blockIdx.x;
    if (!(nwg & 7)) { int cpx = nwg >> 3; id = (id & 7)*cpx + (id >> 3); }
    const int m0 = (id / gridDim.x) * 128, n0 = (id % gridDim.x) * 128;

    f32x4 acc[4][4] = {};

    int srow[2], sq[2], slbase[2];
    #pragma unroll
    for (int r = 0; r < 2; ++r) {
        int row = wave*32 + r*16 + (lane >> 2);
        srow[r]   = row;
        sq[r]     = (lane & 3) ^ ((row >> 1) & 3);
        slbase[r] = wave*1024 + r*512;
    }

    const int fr = lane & 15, fq = lane >> 4;

    for (int kt = 0; kt < K; kt += 32) {
        __syncthreads();
        #pragma unroll
        for (int r = 0; r < 2; ++r) {
            size_t ga = (size_t)(m0 + srow[r]) * K + kt + sq[r]*8;
            size_t gb = (size_t)(n0 + srow[r]) * K + kt + sq[r]*8;
            gload16(A_hi  + ga, lds          + slbase[r]);
            gload16(A_lo  + ga, lds + 4096   + slbase[r]);
            gload16(Bt_hi + gb, lds + 8192   + slbase[r]);
            gload16(Bt_lo + gb, lds + 12288  + slbase[r]);
        }
        __syncthreads();

        short8v ah[4], al[4], bh[4], bl[4];
        #pragma unroll
        for (int i = 0; i < 4; ++i) {
            int rowa = wr*64 + i*16 + fr;
            int offa = rowa*32 + ((fq ^ ((rowa >> 1) & 3)) * 8);
            ah[i] = *(const short8v*)(lds + offa);
            al[i] = *(const short8v*)(lds + 4096 + offa);
            int rowb = wc*64 + i*16 + fr;
            int offb = rowb*32 + ((fq ^ ((rowb >> 1) & 3)) * 8);
            bh[i] = *(const short8v*)(lds + 8192 + offb);
            bl[i] = *(const short8v*)(lds + 12288 + offb);
        }
        #pragma unroll
        for (int i = 0; i < 4; ++i)
            #pragma unroll
            for (int j = 0; j < 4; ++j) {
                acc[i][j] = __builtin_amdgcn_mfma_f32_16x16x32_bf16(ah[i], bh[j], acc[i][j], 0, 0, 0);
                acc[i][j] = __builtin_amdgcn_mfma_f32_16x16x32_bf16(ah[i], bl[j], acc[i][j], 0, 0, 0);
                acc[i][j] = __builtin_amdgcn_mfma_f32_16x16x32_bf16(al[i], bh[j], acc[i][j], 0, 0, 0);
            }
    }

    #pragma unroll
    for (int i = 0; i < 4; ++i)
        #pragma unroll
        for (int j = 0; j < 4; ++j)
            #pragma unroll
            for (int r = 0; r < 4; ++r) {
                int row = m0 + wr*64 + i*16 + fq*4 + r;
                int col = n0 + wc*64 + j*16 + fr;
                float t = tanhf(acc[i][j][r]);
                size_t idx = (size_t)row*N + col;
                if (Cf) Cf[idx] = t;
                if (C_hi) {
                    ushort_t h = f2bf(t);
                    C_hi[idx] = h;
                    C_lo[idx] = f2bf(t - bf2f(h));
                }
            }
}

// ---------------- MFMA assignment: argmin_c (c2[c] - 2 * se.cent) ----------------
__global__ __launch_bounds__(256) void k_assign_mfma(
    const ushort_t* __restrict__ SEh, const ushort_t* __restrict__ SEl,
    const ushort_t* __restrict__ ch, const ushort_t* __restrict__ cl,
    const float* __restrict__ c2,
    int* __restrict__ sc, float* __restrict__ out_w)
{
    __shared__ ushort_t lds[16384];
    __shared__ float c2s[512];
    __shared__ float redD[128][2];
    __shared__ int   redI[128][2];

    const int modal = blockIdx.y;
    const int t0 = blockIdx.x * 128;
    const int tid  = threadIdx.x;
    const int wave = tid >> 6, lane = tid & 63;
    const int wr = wave >> 1, wc = wave & 1;
    const int fr = lane & 15, fq = lane >> 4;

    const ushort_t* seh = SEh + (size_t)modal * NTOK * 256;
    const ushort_t* sel = SEl + (size_t)modal * NTOK * 256;

    c2s[tid] = c2[tid];
    c2s[tid + 256] = c2[tid + 256];

    int srow[2], sq[2], slbase[2];
    #pragma unroll
    for (int r = 0; r < 2; ++r) {
        int row = wave*32 + r*16 + (lane >> 2);
        srow[r]   = row;
        sq[r]     = (lane & 3) ^ ((row >> 1) & 3);
        slbase[r] = wave*1024 + r*512;
    }

    float bd[16]; int bi[16];
    #pragma unroll
    for (int s = 0; s < 16; ++s) { bd[s] = 3.4e38f; bi[s] = 0; }

    for (int j = 0; j < 4; ++j) {
        f32x4 acc[4][4] = {};
        for (int kt = 0; kt < 256; kt += 32) {
            __syncthreads();
            #pragma unroll
            for (int r = 0; r < 2; ++r) {
                size_t ga = (size_t)(t0 + srow[r]) * 256 + kt + sq[r]*8;
                size_t gc = (size_t)(j*128 + srow[r]) * 256 + kt + sq[r]*8;
                gload16(seh + ga, lds          + slbase[r]);
                gload16(sel + ga, lds + 4096   + slbase[r]);
                gload16(ch  + gc, lds + 8192   + slbase[r]);
                gload16(cl  + gc, lds + 12288  + slbase[r]);
            }
            __syncthreads();

            short8v ah[4], al[4], bh[4], bl[4];
            #pragma unroll
            for (int i = 0; i < 4; ++i) {
                int rowa = wr*64 + i*16 + fr;
                int offa = rowa*32 + ((fq ^ ((rowa >> 1) & 3)) * 8);
                ah[i] = *(const short8v*)(lds + offa);
                al[i] = *(const short8v*)(lds + 4096 + offa);
                int rowb = wc*64 + i*16 + fr;
                int offb = rowb*32 + ((fq ^ ((rowb >> 1) & 3)) * 8);
                bh[i] = *(const short8v*)(lds + 8192 + offb);
                bl[i] = *(const short8v*)(lds + 12288 + offb);
            }
            #pragma unroll
            for (int i = 0; i < 4; ++i)
                #pragma unroll
                for (int jj = 0; jj < 4; ++jj) {
                    acc[i][jj] = __builtin_amdgcn_mfma_f32_16x16x32_bf16(ah[i], bh[jj], acc[i][jj], 0, 0, 0);
                    acc[i][jj] = __builtin_amdgcn_mfma_f32_16x16x32_bf16(ah[i], bl[jj], acc[i][jj], 0, 0, 0);
                    acc[i][jj] = __builtin_amdgcn_mfma_f32_16x16x32_bf16(al[i], bh[jj], acc[i][jj], 0, 0, 0);
                }
        }
        #pragma unroll
        for (int i = 0; i < 4; ++i)
            #pragma unroll
            for (int jj = 0; jj < 4; ++jj) {
                int col = j*128 + wc*64 + jj*16 + fr;
                float cc = c2s[col];
                #pragma unroll
                for (int r = 0; r < 4; ++r) {
                    float d = cc - 2.f * acc[i][jj][r];
                    int s = i*4 + r;
                    if (d < bd[s]) { bd[s] = d; bi[s] = col; }
                }
            }
    }

    #pragma unroll
    for (int s = 0; s < 16; ++s) {
        #pragma unroll
        for (int off = 1; off < 16; off <<= 1) {
            float od = __shfl_xor(bd[s], off);
            int   oi = __shfl_xor(bi[s], off);
            if (od < bd[s] || (od == bd[s] && oi < bi[s])) { bd[s] = od; bi[s] = oi; }
        }
    }
    if (fr == 0) {
        #pragma unroll
        for (int i = 0; i < 4; ++i)
            #pragma unroll
            for (int r = 0; r < 4; ++r) {
                int tl = wr*64 + i*16 + fq*4 + r;
                redD[tl][wc] = bd[i*4 + r];
                redI[tl][wc] = bi[i*4 + r];
            }
    }
    __syncthreads();
    if (tid < 128) {
        float d0 = redD[tid][0], d1 = redD[tid][1];
        int   i0 = redI[tid][0], i1 = redI[tid][1];
        if (d1 < d0 || (d1 == d0 && i1 < i0)) { d0 = d1; i0 = i1; }
        int g = t0 + tid;
        sc[modal*NTOK + g] = i0;
        out_w[OFF_SC + (size_t)modal*NTOK + g] = (float)i0;
    }
}

// ---------------- fp32 fallback assignment ----------------
__global__ __launch_bounds__(256) void k_assign(
    const float* __restrict__ out_ro,
    const float* __restrict__ c2,
    int* __restrict__ sc,
    float* __restrict__ out_w)
{
    const int modal = blockIdx.y;
    const int tok0 = blockIdx.x * 64;
    const float* se   = out_ro + OFF_SE + (size_t)modal * NTOK * 256;
    const float* cent = out_ro + OFF_CENT;

    __shared__ float4 se4[64][64];
    __shared__ float4 ct4[64][64];

    const int tid = threadIdx.x;
    const int tt = tid & 15, cc = tid >> 4;

    {
        int rbase = tid >> 6;
        int d4 = tid & 63;
        #pragma unroll
        for (int i = 0; i < 16; ++i) {
            int t = i*4 + rbase;
            float4 v = *(const float4*)(se + (size_t)(tok0 + t)*256 + d4*4);
            se4[t][d4 ^ (t >> 2)] = v;
        }
    }
    __syncthreads();

    float e2r[4];
    #pragma unroll
    for (int k2 = 0; k2 < 4; ++k2) {
        float s = 0.f;
        for (int d4 = 0; d4 < 64; ++d4) {
            float4 v = se4[4*tt + k2][d4 ^ tt];
            s += dot4(v, v);
        }
        e2r[k2] = s;
    }

    float bd[4]; int bi[4];
    #pragma unroll
    for (int k2 = 0; k2 < 4; ++k2) { bd[k2] = 3.4e38f; bi[k2] = 0; }

    for (int ctile = 0; ctile < 8; ++ctile) {
        int c0 = ctile * 64;
        {
            int rbase = tid >> 6;
            int d4 = tid & 63;
            #pragma unroll
            for (int i = 0; i < 16; ++i) {
                int r = i*4 + rbase;
                float4 v = *(const float4*)(cent + (size_t)(c0 + r)*256 + d4*4);
                ct4[r][d4 ^ (r >> 2)] = v;
            }
        }
        __syncthreads();

        float accd[4][4];
        #pragma unroll
        for (int a = 0; a < 4; ++a)
            #pragma unroll
            for (int b = 0; b < 4; ++b) accd[a][b] = 0.f;

        for (int d4 = 0; d4 < 64; ++d4) {
            float4 sv[4], cv[4];
            #pragma unroll
            for (int k2 = 0; k2 < 4; ++k2) sv[k2] = se4[4*tt + k2][d4 ^ tt];
            #pragma unroll
            for (int jx = 0; jx < 4; ++jx) cv[jx] = ct4[4*cc + jx][d4 ^ cc];
            #pragma unroll
            for (int k2 = 0; k2 < 4; ++k2)
                #pragma unroll
                for (int jx = 0; jx < 4; ++jx)
                    accd[k2][jx] += dot4(sv[k2], cv[jx]);
        }

        #pragma unroll
        for (int jx = 0; jx < 4; ++jx) {
            int cidx = c0 + 4*cc + jx;
            float cj = c2[cidx];
            #pragma unroll
            for (int k2 = 0; k2 < 4; ++k2) {
                float d = cj + e2r[k2] - 2.f * accd[k2][jx];
                if (d < bd[k2]) { bd[k2] = d; bi[k2] = cidx; }
            }
        }
        __syncthreads();
    }

    float* red_d = (float*)ct4;
    int*   red_i = (int*)ct4 + 64*17;
    #pragma unroll
    for (int k2 = 0; k2 < 4; ++k2) {
        red_d[(4*tt + k2)*17 + cc] = bd[k2];
        red_i[(4*tt + k2)*17 + cc] = bi[k2];
    }
    __syncthreads();
    if (tid < 64) {
        float b = red_d[tid*17]; int ix = red_i[tid*17];
        #pragma unroll
        for (int q = 1; q < 16; ++q) {
            float d = red_d[tid*17 + q]; int i2 = red_i[tid*17 + q];
            if (d < b || (d == b && i2 < ix)) { b = d; ix = i2; }
        }
        int g = tok0 + tid;
        sc[modal*NTOK + g] = ix;
        out_w[OFF_SC + (size_t)modal*NTOK + g] = (float)ix;
    }
}

// ---------------- stable counting sort ----------------
__global__ __launch_bounds__(256) void k_hist(const int* __restrict__ sc,
                                              int* __restrict__ blockHist)
{
    int modal = blockIdx.y, blk = blockIdx.x, tid = threadIdx.x;
    __shared__ int h[512];
    h[tid] = 0; h[tid + 256] = 0;
    __syncthreads();
    atomicAdd(&h[sc[modal*NTOK + blk*256 + tid]], 1);
    __syncthreads();
    int base = (modal*128 + blk) * 512;
    blockHist[base + tid]       = h[tid];
    blockHist[base + tid + 256] = h[tid + 256];
}

__global__ __launch_bounds__(512) void k_scan(const int* __restrict__ blockHist,
                                              int* __restrict__ blockBase,
                                              int* __restrict__ classBase,
                                              float* __restrict__ out)
{
    int modal = blockIdx.x;
    int c = threadIdx.x;
    int run = 0;
    for (int b = 0; b < 128; ++b) {
        int idx = (modal*128 + b)*512 + c;
        blockBase[idx] = run;
        run += blockHist[idx];
    }
    float* cnt = out + (modal ? OFF_CI : OFF_CT);
    cnt[c] = (float)run;

    __shared__ int s[512];
    s[c] = run;
    __syncthreads();
    int total = run;
    for (int off = 1; off < 512; off <<= 1) {
        int v = 0;
        if (c >= off) v = s[c - off];
        __syncthreads();
        s[c] += v;
        __syncthreads();
    }
    classBase[modal*512 + c] = s[c] - total;
}

__global__ __launch_bounds__(256) void k_scatter(const int* __restrict__ sc,
                                                 const int* __restrict__ blockBase,
                                                 const int* __restrict__ classBase,
                                                 float* __restrict__ out)
{
    int modal = blockIdx.y, blk = blockIdx.x, tid = threadIdx.x;
    __shared__ int cls[256];
    int t = blk*256 + tid;
    int c = sc[modal*NTOK + t];
    cls[tid] = c;
    __syncthreads();
    int rank = 0;
    for (int j = 0; j < tid; ++j) rank += (cls[j] == c) ? 1 : 0;
    int pos = classBase[modal*512 + c] + blockBase[(modal*128 + blk)*512 + c] + rank;
    float* oo = out + (modal ? OFF_OI : OFF_OT);
    oo[pos] = (float)t;
}

extern "C" void kernel_launch(void* const* d_in, const int* in_sizes, int n_in,
                              void* d_out, int out_size, void* d_ws, size_t ws_size,
                              hipStream_t stream)
{
    const float* text_emb  = (const float*)d_in[0];
    const float* image_emb = (const float*)d_in[1];
    const float* W[2][3] = {
        {(const float*)d_in[2], (const float*)d_in[3], (const float*)d_in[4]},
        {(const float*)d_in[5], (const float*)d_in[6], (const float*)d_in[7]}
    };
    const float* cent_raw = (const float*)d_in[8];
    float* out = (float*)d_out;
    char* w = (char*)d_ws;

    int*   sc        = (int*)w;
    int*   blockHist = (int*)(w + 0x40000);
    int*   blockBase = (int*)(w + 0xC0000);
    int*   classBase = (int*)(w + 0x140000);
    float* c2        = (float*)(w + 0x141000);
    ushort_t* cent_h = (ushort_t*)(w + 0x142000);
    ushort_t* cent_l = (ushort_t*)(w + 0x182000);

    ushort_t* wreg = (ushort_t*)(w + 0x200000);
    const size_t WM = 4*1048576 + 2*262144;

    ushort_t* SEh = (ushort_t*)(w + 0x1400000);
    ushort_t* SEl = (ushort_t*)(w + 0x3400000);

    bool mfmaAssign = true;
    size_t actoff = 0x5400000;
    int Mc = 0;
    for (int c = NTOK; c >= 128; c >>= 1)
        if (actoff + (size_t)c*8192 <= ws_size) { Mc = c; break; }
    if (Mc == 0) {
        mfmaAssign = false;
        actoff = 0x1400000;
        for (int c = NTOK; c >= 128; c >>= 1)
            if (actoff + (size_t)c*8192 <= ws_size) { Mc = c; break; }
        if (Mc == 0) Mc = 128;
    }
    ushort_t* act = (ushort_t*)(w + actoff);
    const bool big = (Mc % 256 == 0);

    k_cent<<<dim3(512), dim3(64), 0, stream>>>(cent_raw, out, c2, cent_h, cent_l);
    k_wc  <<<dim3(64),  dim3(256), 0, stream>>>(out);

    for (int m = 0; m < 2; ++m) {
        const float* emb = m ? image_emb : text_emb;
        ushort_t* w1h = wreg + (size_t)m*WM;
        ushort_t* w1l = w1h + 1048576;
        ushort_t* w2h = w1l + 1048576;
        ushort_t* w2l = w2h + 1048576;
        ushort_t* w3h = w2l + 1048576;
        ushort_t* w3l = w3h + 262144;

        k_wsplit<<<dim3(32, 32), dim3(256), 0, stream>>>(W[m][0], w1h, w1l, 1024, 1024);
        k_wsplit<<<dim3(32, 32), dim3(256), 0, stream>>>(W[m][1], w2h, w2l, 1024, 1024);
        k_wsplit<<<dim3(8,  32), dim3(256), 0, stream>>>(W[m][2], w3h, w3l, 1024, 256);

        ushort_t* Ah = act;
        ushort_t* Al = Ah + (size_t)Mc*1024;
        ushort_t* Hh = Al + (size_t)Mc*1024;
        ushort_t* Hl = Hh + (size_t)Mc*1024;

        for (int s0 = 0; s0 < NTOK; s0 += Mc) {
            long n4 = (long)Mc*1024/4;
            k_esplit<<<dim3((unsigned)((n4 + 255)/256)), dim3(256), 0, stream>>>(
                emb + (size_t)s0*1024, Ah, Al, n4);
            if (big) {
                k_gemm_mfma256<<<dim3((Mc/256)*4), dim3(512), 0, stream>>>(
                    Ah, w1h, Hh, Hl, (unsigned)Mc*1024u, 1048576u, 1024);
                k_gemm_mfma256<<<dim3((Mc/256)*4), dim3(512), 0, stream>>>(
                    Hh, w2h, Ah, Al, (unsigned)Mc*1024u, 1048576u, 1024);
            } else {
                k_gemm_mfma<<<dim3(8, Mc/128), dim3(256), 0, stream>>>(
                    Ah, Al, w1h, w1l, Hh, Hl, nullptr, 1024);
                k_gemm_mfma<<<dim3(8, Mc/128), dim3(256), 0, stream>>>(
                    Hh, Hl, w2h, w2l, Ah, Al, nullptr, 1024);
            }
            ushort_t* seh_ptr = mfmaAssign ? SEh + ((size_t)m*NTOK + s0)*256 : nullptr;
            ushort_t* sel_ptr = mfmaAssign ? SEl + ((size_t)m*NTOK + s0)*256 : nullptr;
            k_gemm_mfma<<<dim3(2, Mc/128), dim3(256), 0, stream>>>(
                Ah, Al, w3h, w3l, seh_ptr, sel_ptr,
                out + OFF_SE + ((size_t)m*NTOK + s0)*256, 256);
        }
    }

    if (mfmaAssign) {
        k_assign_mfma<<<dim3(256, 2), dim3(256), 0, stream>>>(
            SEh, SEl, cent_h, cent_l, c2, sc, out);
    } else {
        k_assign<<<dim3(512, 2), dim3(256), 0, stream>>>(out, c2, sc, out);
    }
    k_hist   <<<dim3(128, 2), dim3(256), 0, stream>>>(sc, blockHist);
    k_scan   <<<dim3(2),      dim3(512), 0, stream>>>(blockHist, blockBase, classBase, out);
    k_scatter<<<dim3(128, 2), dim3(256), 0, stream>>>(sc, blockBase, classBase, out);
}

// Round 8
// 1045.144 us; speedup vs baseline: 1.1076x; 1.0414x over previous
//
#include <hip/hip_runtime.h>
#include <math.h>

#define NTOK 32768
typedef unsigned short ushort_t;

// d_out offsets (in floats)
#define OFF_CENT 0
#define OFF_SE   131072
#define OFF_WC   16908288
#define OFF_SC   16973824
#define OFF_OT   17039360
#define OFF_CT   17072128
#define OFF_OI   17072640
#define OFF_CI   17105408

typedef __attribute__((ext_vector_type(8))) short short8v;
typedef __attribute__((ext_vector_type(4))) float f32x4;

__device__ __forceinline__ float dot4(float4 a, float4 b){
    return a.x*b.x + a.y*b.y + a.z*b.z + a.w*b.w;
}

// RNE float -> bf16 bits
__device__ __forceinline__ ushort_t f2bf(float x){
    unsigned int u = __float_as_uint(x);
    unsigned int r = (u + 0x7fffu + ((u >> 16) & 1u)) >> 16;
    return (ushort_t)r;
}
__device__ __forceinline__ float bf2f(ushort_t h){
    return __uint_as_float(((unsigned int)h) << 16);
}

__device__ __forceinline__ void gload16(const void* g, void* l){
    __builtin_amdgcn_global_load_lds(
        (const __attribute__((address_space(1))) void*)g,
        (__attribute__((address_space(3))) void*)l,
        16, 0, 0);
}

// split 8 fp32 -> 8 bf16 hi + 8 bf16 lo (bit-identical to k_esplit)
__device__ __forceinline__ void cvt8(float4 a, float4 b, short8v& h, short8v& l){
    float x[8] = {a.x, a.y, a.z, a.w, b.x, b.y, b.z, b.w};
    #pragma unroll
    for (int i = 0; i < 8; ++i) {
        ushort_t hh = f2bf(x[i]);
        h[i] = (short)hh;
        l[i] = (short)f2bf(x[i] - bf2f(hh));
    }
}

// ---------------- centroids: tanh + c2 + hi/lo split ----------------
__global__ __launch_bounds__(64) void k_cent(const float* __restrict__ raw,
                                             float* __restrict__ out,
                                             float* __restrict__ c2,
                                             ushort_t* __restrict__ ch,
                                             ushort_t* __restrict__ cl)
{
    int c = blockIdx.x, l = threadIdx.x;
    float4 v = *(const float4*)(raw + (size_t)c*256 + l*4);
    float4 t;
    t.x = tanhf(v.x); t.y = tanhf(v.y); t.z = tanhf(v.z); t.w = tanhf(v.w);
    *(float4*)(out + OFF_CENT + (size_t)c*256 + l*4) = t;
    ushort4 h = make_ushort4(f2bf(t.x), f2bf(t.y), f2bf(t.z), f2bf(t.w));
    ushort4 lo = make_ushort4(f2bf(t.x - bf2f(h.x)), f2bf(t.y - bf2f(h.y)),
                              f2bf(t.z - bf2f(h.z)), f2bf(t.w - bf2f(h.w)));
    *(ushort4*)(ch + (size_t)c*256 + l*4) = h;
    *(ushort4*)(cl + (size_t)c*256 + l*4) = lo;
    float s = dot4(t, t);
    #pragma unroll
    for (int off = 32; off > 0; off >>= 1) s += __shfl_down(s, off);
    if (l == 0) c2[c] = s;
}

// ---------------- word_class fill ----------------
__global__ __launch_bounds__(256) void k_wc(float* __restrict__ out)
{
    int g = blockIdx.x*256 + threadIdx.x;
    float v = (g*4 < NTOK) ? 0.f : 1.f;
    float4* p = (float4*)(out + OFF_WC);
    p[g] = make_float4(v, v, v, v);
}

// ---------------- emb split (fallback path only) ----------------
__global__ __launch_bounds__(256) void k_esplit(const float* __restrict__ x,
                                                ushort_t* __restrict__ hi,
                                                ushort_t* __restrict__ lo,
                                                long n4)
{
    long g = (long)blockIdx.x*256 + threadIdx.x;
    if (g >= n4) return;
    float4 v = ((const float4*)x)[g];
    ushort_t h0 = f2bf(v.x), h1 = f2bf(v.y), h2 = f2bf(v.z), h3 = f2bf(v.w);
    ushort4 h = make_ushort4(h0, h1, h2, h3);
    ushort4 l = make_ushort4(f2bf(v.x - bf2f(h0)), f2bf(v.y - bf2f(h1)),
                             f2bf(v.z - bf2f(h2)), f2bf(v.w - bf2f(h3)));
    ((ushort4*)hi)[g] = h;
    ((ushort4*)lo)[g] = l;
}

// ---------------- weight transpose + split ----------------
__global__ __launch_bounds__(256) void k_wsplit(const float* __restrict__ W,
                                                ushort_t* __restrict__ Wt_hi,
                                                ushort_t* __restrict__ Wt_lo,
                                                int K, int N)
{
    __shared__ float t[32][33];
    int k0 = blockIdx.y*32, n0 = blockIdx.x*32;
    int tx = threadIdx.x & 31, ty = threadIdx.x >> 5;
    #pragma unroll
    for (int r = 0; r < 4; ++r)
        t[ty + r*8][tx] = W[(size_t)(k0 + ty + r*8)*N + n0 + tx];
    __syncthreads();
    #pragma unroll
    for (int r = 0; r < 4; ++r) {
        int n = ty + r*8;
        float x = t[tx][n];
        ushort_t h = f2bf(x);
        Wt_hi[(size_t)(n0+n)*K + k0 + tx] = h;
        Wt_lo[(size_t)(n0+n)*K + k0 + tx] = f2bf(x - bf2f(h));
    }
}

// ================= layer-1: fused fp32-A split + 256x256 split-bf16 GEMM + tanh ======
// A is fp32 [M][1024]; staged via regs (load fp32 -> cvt hi/lo -> ds_write).
// B (weights) staged via global_load_lds as usual. Same LDS layout/swizzle as mfma256.
__global__ __launch_bounds__(512, 2) void k_gemm_l1(
    const float* __restrict__ Af, const ushort_t* __restrict__ Bt_hi,
    ushort_t* __restrict__ C_hi, ushort_t* __restrict__ C_lo,
    unsigned bDelta, int N)
{
    __shared__ ushort_t lds[65536];   // 2 x { Ah Al Bh Bl } each [256][32]

    const int tid  = threadIdx.x;
    const int wave = tid >> 6, lane = tid & 63;
    const int wr = wave >> 2, wc = wave & 3;
    const int fr = lane & 15, fq = lane >> 4;

    int nwg = gridDim.x;
    int id = blockIdx.x;
    if (!(nwg & 7)) { int cpx = nwg >> 3; id = (id & 7)*cpx + (id >> 3); }
    const int nx = N >> 8;
    const int n0 = (id % nx) * 256;
    const int m0 = (id / nx) * 256;

    const int srow0 = tid >> 2;
    const int qx = (tid & 3) ^ ((srow0 >> 1) & 3);

    // A fp32 source (pre-swizzled column)
    const float* fA0 = Af + (size_t)(m0 + srow0) * 1024 + qx*8;
    const float* fA1 = fA0 + 131072;               // +128 rows
    // B bf16 source
    const unsigned offB0 = (unsigned)(n0 + srow0) * 1024u + (unsigned)qx * 8u;
    const ushort_t* pB0  = Bt_hi + offB0;
    const ushort_t* pB1  = pB0 + 131072u;
    const ushort_t* pB0l = pB0 + bDelta;
    const ushort_t* pB1l = pB1 + bDelta;
    const unsigned ldsS0 = (unsigned)wave * 512u;
    const unsigned ldsS1 = ldsS0 + 4096u;
    const unsigned wOff  = ldsS0 + (unsigned)lane * 8u;   // A ds_write dest (elements)

    const unsigned fb = (unsigned)fr*32u + (unsigned)((fq ^ ((fr >> 1) & 3)) * 8);
    const ushort_t* p0 = lds + fb;
    const ushort_t* p1 = p0 + 32768u;

    f32x4 acc[8][4] = {};

#define STGB(KT, WB) { \
    unsigned wb_ = (unsigned)(WB) * 32768u; \
    gload16(pB0  + (KT), lds + wb_ + 16384u + ldsS0); \
    gload16(pB1  + (KT), lds + wb_ + 16384u + ldsS1); \
    gload16(pB0l + (KT), lds + wb_ + 24576u + ldsS0); \
    gload16(pB1l + (KT), lds + wb_ + 24576u + ldsS1); \
}
#define RA1(P, hl, i) (*(const short8v*)((P) + (hl)*8192u + (unsigned)wr*4096u + (unsigned)(i)*512u))
#define RB1(P, hl, j) (*(const short8v*)((P) + 16384u + (hl)*8192u + (unsigned)wc*2048u + (unsigned)(j)*512u))
#define MM16(A8, B8, C4) __builtin_amdgcn_mfma_f32_16x16x32_bf16(A8, B8, C4, 0, 0, 0)

    // prologue: stage tile 0 into buf 0 (A via regs, B via DMA)
    {
        float4 a00 = *(const float4*)(fA0);
        float4 a01 = *(const float4*)(fA0 + 4);
        float4 a10 = *(const float4*)(fA1);
        float4 a11 = *(const float4*)(fA1 + 4);
        STGB(0, 0);
        short8v h0, l0, h1, l1;
        cvt8(a00, a01, h0, l0);
        cvt8(a10, a11, h1, l1);
        *(short8v*)(lds + wOff)          = h0;
        *(short8v*)(lds + 4096u + wOff)  = h1;
        *(short8v*)(lds + 8192u + wOff)  = l0;
        *(short8v*)(lds + 12288u + wOff) = l1;
    }
    __syncthreads();

    #pragma unroll 1
    for (int kt = 0; kt < 1024; kt += 32) {
        const int par = (kt >> 5) & 1;
        const ushort_t* cp = par ? p1 : p0;
        const bool pf = (kt + 32) < 1024;

        // issue next-tile A fp32 loads + B DMA early
        float4 a00, a01, a10, a11;
        if (pf) {
            a00 = *(const float4*)(fA0 + kt + 32);
            a01 = *(const float4*)(fA0 + kt + 36);
            a10 = *(const float4*)(fA1 + kt + 32);
            a11 = *(const float4*)(fA1 + kt + 36);
            STGB(kt + 32, par ^ 1);
        }

        short8v bh0 = RB1(cp,0,0), bl0 = RB1(cp,1,0);
        short8v bh1 = RB1(cp,0,1), bl1 = RB1(cp,1,1);
        short8v bh2 = RB1(cp,0,2), bl2 = RB1(cp,1,2);
        short8v bh3 = RB1(cp,0,3), bl3 = RB1(cp,1,3);

        __builtin_amdgcn_s_setprio(1);
        #pragma unroll
        for (int i = 0; i < 8; ++i) {
            short8v ah = RA1(cp,0,i), al = RA1(cp,1,i);
            acc[i][0] = MM16(ah, bh0, acc[i][0]);
            acc[i][1] = MM16(ah, bh1, acc[i][1]);
            acc[i][2] = MM16(ah, bh2, acc[i][2]);
            acc[i][3] = MM16(ah, bh3, acc[i][3]);
            acc[i][0] = MM16(ah, bl0, acc[i][0]);
            acc[i][1] = MM16(ah, bl1, acc[i][1]);
            acc[i][2] = MM16(ah, bl2, acc[i][2]);
            acc[i][3] = MM16(ah, bl3, acc[i][3]);
            acc[i][0] = MM16(al, bh0, acc[i][0]);
            acc[i][1] = MM16(al, bh1, acc[i][1]);
            acc[i][2] = MM16(al, bh2, acc[i][2]);
            acc[i][3] = MM16(al, bh3, acc[i][3]);
        }
        __builtin_amdgcn_s_setprio(0);

        // write next tile's A (regs -> LDS buf^1), then boundary barrier
        if (pf) {
            unsigned wb = (unsigned)(par ^ 1) * 32768u;
            short8v h0, l0, h1, l1;
            cvt8(a00, a01, h0, l0);
            cvt8(a10, a11, h1, l1);
            *(short8v*)(lds + wb + wOff)          = h0;
            *(short8v*)(lds + wb + 4096u + wOff)  = h1;
            *(short8v*)(lds + wb + 8192u + wOff)  = l0;
            *(short8v*)(lds + wb + 12288u + wOff) = l1;
        }
        __syncthreads();
    }

    // epilogue: C/D layout col = lane&15, row = (lane>>4)*4 + reg
    #pragma unroll
    for (int i = 0; i < 8; ++i)
        #pragma unroll
        for (int j = 0; j < 4; ++j)
            #pragma unroll
            for (int r = 0; r < 4; ++r) {
                int row = m0 + wr*128 + i*16 + fq*4 + r;
                int col = n0 + wc*64 + j*16 + fr;
                float t = tanhf(acc[i][j][r]);
                size_t idx = (size_t)row*N + col;
                ushort_t h = f2bf(t);
                C_hi[idx] = h;
                C_lo[idx] = f2bf(t - bf2f(h));
            }
#undef STGB
#undef RA1
#undef RB1
#undef MM16
}

// ================= 256x256 8-wave split-bf16 GEMM + tanh, 16x16x32 MFMA ==========
__global__ __launch_bounds__(512, 2) void k_gemm_mfma256(
    const ushort_t* __restrict__ A_hi, const ushort_t* __restrict__ Bt_hi,
    ushort_t* __restrict__ C_hi, ushort_t* __restrict__ C_lo,
    unsigned aDelta, unsigned bDelta, int N)
{
    __shared__ ushort_t lds[65536];

    const int tid  = threadIdx.x;
    const int wave = tid >> 6, lane = tid & 63;
    const int wr = wave >> 2, wc = wave & 3;
    const int fr = lane & 15, fq = lane >> 4;

    int nwg = gridDim.x;
    int id = blockIdx.x;
    if (!(nwg & 7)) { int cpx = nwg >> 3; id = (id & 7)*cpx + (id >> 3); }
    const int nx = N >> 8;
    const int n0 = (id % nx) * 256;
    const int m0 = (id / nx) * 256;

    const int srow0 = tid >> 2;
    const int qx = (tid & 3) ^ ((srow0 >> 1) & 3);

    const unsigned offA0 = (unsigned)(m0 + srow0) * 1024u + (unsigned)qx * 8u;
    const unsigned offB0 = (unsigned)(n0 + srow0) * 1024u + (unsigned)qx * 8u;
    const ushort_t* pA0  = A_hi + offA0;
    const ushort_t* pA1  = pA0 + 131072u;
    const ushort_t* pA0l = pA0 + aDelta;
    const ushort_t* pA1l = pA1 + aDelta;
    const ushort_t* pB0  = Bt_hi + offB0;
    const ushort_t* pB1  = pB0 + 131072u;
    const ushort_t* pB0l = pB0 + bDelta;
    const ushort_t* pB1l = pB1 + bDelta;
    const unsigned ldsS0 = (unsigned)wave * 512u;
    const unsigned ldsS1 = ldsS0 + 4096u;

    const unsigned fb = (unsigned)fr*32u + (unsigned)((fq ^ ((fr >> 1) & 3)) * 8);
    const ushort_t* p0 = lds + fb;
    const ushort_t* p1 = p0 + 32768u;

    f32x4 acc[8][4] = {};

#define STG(KT, WB) { \
    unsigned wb_ = (unsigned)(WB) * 32768u; \
    gload16(pA0  + (KT), lds + wb_ +           ldsS0); \
    gload16(pA1  + (KT), lds + wb_ +           ldsS1); \
    gload16(pA0l + (KT), lds + wb_ +  8192u +  ldsS0); \
    gload16(pA1l + (KT), lds + wb_ +  8192u +  ldsS1); \
    gload16(pB0  + (KT), lds + wb_ + 16384u +  ldsS0); \
    gload16(pB1  + (KT), lds + wb_ + 16384u +  ldsS1); \
    gload16(pB0l + (KT), lds + wb_ + 24576u +  ldsS0); \
    gload16(pB1l + (KT), lds + wb_ + 24576u +  ldsS1); \
}
#define RA(P, hl, i) (*(const short8v*)((P) + (hl)*8192u + (unsigned)wr*4096u + (unsigned)(i)*512u))
#define RB(P, hl, j) (*(const short8v*)((P) + 16384u + (hl)*8192u + (unsigned)wc*2048u + (unsigned)(j)*512u))
#define MM16(A8, B8, C4) __builtin_amdgcn_mfma_f32_16x16x32_bf16(A8, B8, C4, 0, 0, 0)

    STG(0, 0);
    __syncthreads();

    #pragma unroll 1
    for (int kt = 0; kt < 1024; kt += 32) {
        const int par = (kt >> 5) & 1;
        const ushort_t* cp = par ? p1 : p0;

        // B fragments first (feeds first MFMAs sooner), then next-tile staging
        short8v bh0 = RB(cp,0,0), bl0 = RB(cp,1,0);
        short8v bh1 = RB(cp,0,1), bl1 = RB(cp,1,1);
        short8v bh2 = RB(cp,0,2), bl2 = RB(cp,1,2);
        short8v bh3 = RB(cp,0,3), bl3 = RB(cp,1,3);

        if (kt + 32 < 1024) STG(kt + 32, par ^ 1);

        __builtin_amdgcn_s_setprio(1);
        #pragma unroll
        for (int i = 0; i < 8; ++i) {
            short8v ah = RA(cp,0,i), al = RA(cp,1,i);
            acc[i][0] = MM16(ah, bh0, acc[i][0]);
            acc[i][1] = MM16(ah, bh1, acc[i][1]);
            acc[i][2] = MM16(ah, bh2, acc[i][2]);
            acc[i][3] = MM16(ah, bh3, acc[i][3]);
            acc[i][0] = MM16(ah, bl0, acc[i][0]);
            acc[i][1] = MM16(ah, bl1, acc[i][1]);
            acc[i][2] = MM16(ah, bl2, acc[i][2]);
            acc[i][3] = MM16(ah, bl3, acc[i][3]);
            acc[i][0] = MM16(al, bh0, acc[i][0]);
            acc[i][1] = MM16(al, bh1, acc[i][1]);
            acc[i][2] = MM16(al, bh2, acc[i][2]);
            acc[i][3] = MM16(al, bh3, acc[i][3]);
        }
        __builtin_amdgcn_s_setprio(0);

        __syncthreads();
    }

    #pragma unroll
    for (int i = 0; i < 8; ++i)
        #pragma unroll
        for (int j = 0; j < 4; ++j)
            #pragma unroll
            for (int r = 0; r < 4; ++r) {
                int row = m0 + wr*128 + i*16 + fq*4 + r;
                int col = n0 + wc*64 + j*16 + fr;
                float t = tanhf(acc[i][j][r]);
                size_t idx = (size_t)row*N + col;
                ushort_t h = f2bf(t);
                C_hi[idx] = h;
                C_lo[idx] = f2bf(t - bf2f(h));
            }
#undef STG
#undef RA
#undef RB
#undef MM16
}

// ---------------- 128x128 split-bf16 MFMA GEMM + tanh (layer 3 / fallback) ----------------
__global__ __launch_bounds__(256, 2) void k_gemm_mfma(
    const ushort_t* __restrict__ A_hi, const ushort_t* __restrict__ A_lo,
    const ushort_t* __restrict__ Bt_hi, const ushort_t* __restrict__ Bt_lo,
    ushort_t* __restrict__ C_hi, ushort_t* __restrict__ C_lo,
    float* __restrict__ Cf,
    int N)
{
    const int K = 1024;
    __shared__ ushort_t lds[16384];

    const int tid  = threadIdx.x;
    const int wave = tid >> 6, lane = tid & 63;
    const int wr = wave >> 1, wc = wave & 1;

    int nwg = gridDim.x * gridDim.y;
    int id = blockIdx.y * gridDim.x + blockIdx.x;
    if (!(nwg & 7)) { int cpx = nwg >> 3; id = (id & 7)*cpx + (id >> 3); }
    const int m0 = (id / gridDim.x) * 128, n0 = (id % gridDim.x) * 128;

    f32x4 acc[4][4] = {};

    int srow[2], sq[2], slbase[2];
    #pragma unroll
    for (int r = 0; r < 2; ++r) {
        int row = wave*32 + r*16 + (lane >> 2);
        srow[r]   = row;
        sq[r]     = (lane & 3) ^ ((row >> 1) & 3);
        slbase[r] = wave*1024 + r*512;
    }

    const int fr = lane & 15, fq = lane >> 4;

    for (int kt = 0; kt < K; kt += 32) {
        __syncthreads();
        #pragma unroll
        for (int r = 0; r < 2; ++r) {
            size_t ga = (size_t)(m0 + srow[r]) * K + kt + sq[r]*8;
            size_t gb = (size_t)(n0 + srow[r]) * K + kt + sq[r]*8;
            gload16(A_hi  + ga, lds          + slbase[r]);
            gload16(A_lo  + ga, lds + 4096   + slbase[r]);
            gload16(Bt_hi + gb, lds + 8192   + slbase[r]);
            gload16(Bt_lo + gb, lds + 12288  + slbase[r]);
        }
        __syncthreads();

        short8v ah[4], al[4], bh[4], bl[4];
        #pragma unroll
        for (int i = 0; i < 4; ++i) {
            int rowa = wr*64 + i*16 + fr;
            int offa = rowa*32 + ((fq ^ ((rowa >> 1) & 3)) * 8);
            ah[i] = *(const short8v*)(lds + offa);
            al[i] = *(const short8v*)(lds + 4096 + offa);
            int rowb = wc*64 + i*16 + fr;
            int offb = rowb*32 + ((fq ^ ((rowb >> 1) & 3)) * 8);
            bh[i] = *(const short8v*)(lds + 8192 + offb);
            bl[i] = *(const short8v*)(lds + 12288 + offb);
        }
        #pragma unroll
        for (int i = 0; i < 4; ++i)
            #pragma unroll
            for (int j = 0; j < 4; ++j) {
                acc[i][j] = __builtin_amdgcn_mfma_f32_16x16x32_bf16(ah[i], bh[j], acc[i][j], 0, 0, 0);
                acc[i][j] = __builtin_amdgcn_mfma_f32_16x16x32_bf16(ah[i], bl[j], acc[i][j], 0, 0, 0);
                acc[i][j] = __builtin_amdgcn_mfma_f32_16x16x32_bf16(al[i], bh[j], acc[i][j], 0, 0, 0);
            }
    }

    #pragma unroll
    for (int i = 0; i < 4; ++i)
        #pragma unroll
        for (int j = 0; j < 4; ++j)
            #pragma unroll
            for (int r = 0; r < 4; ++r) {
                int row = m0 + wr*64 + i*16 + fq*4 + r;
                int col = n0 + wc*64 + j*16 + fr;
                float t = tanhf(acc[i][j][r]);
                size_t idx = (size_t)row*N + col;
                if (Cf) Cf[idx] = t;
                if (C_hi) {
                    ushort_t h = f2bf(t);
                    C_hi[idx] = h;
                    C_lo[idx] = f2bf(t - bf2f(h));
                }
            }
}

// ---------------- MFMA assignment: argmin_c (c2[c] - 2 * se.cent) ----------------
__global__ __launch_bounds__(256) void k_assign_mfma(
    const ushort_t* __restrict__ SEh, const ushort_t* __restrict__ SEl,
    const ushort_t* __restrict__ ch, const ushort_t* __restrict__ cl,
    const float* __restrict__ c2,
    int* __restrict__ sc, float* __restrict__ out_w)
{
    __shared__ ushort_t lds[16384];
    __shared__ float c2s[512];
    __shared__ float redD[128][2];
    __shared__ int   redI[128][2];

    const int modal = blockIdx.y;
    const int t0 = blockIdx.x * 128;
    const int tid  = threadIdx.x;
    const int wave = tid >> 6, lane = tid & 63;
    const int wr = wave >> 1, wc = wave & 1;
    const int fr = lane & 15, fq = lane >> 4;

    const ushort_t* seh = SEh + (size_t)modal * NTOK * 256;
    const ushort_t* sel = SEl + (size_t)modal * NTOK * 256;

    c2s[tid] = c2[tid];
    c2s[tid + 256] = c2[tid + 256];

    int srow[2], sq[2], slbase[2];
    #pragma unroll
    for (int r = 0; r < 2; ++r) {
        int row = wave*32 + r*16 + (lane >> 2);
        srow[r]   = row;
        sq[r]     = (lane & 3) ^ ((row >> 1) & 3);
        slbase[r] = wave*1024 + r*512;
    }

    float bd[16]; int bi[16];
    #pragma unroll
    for (int s = 0; s < 16; ++s) { bd[s] = 3.4e38f; bi[s] = 0; }

    for (int j = 0; j < 4; ++j) {
        f32x4 acc[4][4] = {};
        for (int kt = 0; kt < 256; kt += 32) {
            __syncthreads();
            #pragma unroll
            for (int r = 0; r < 2; ++r) {
                size_t ga = (size_t)(t0 + srow[r]) * 256 + kt + sq[r]*8;
                size_t gc = (size_t)(j*128 + srow[r]) * 256 + kt + sq[r]*8;
                gload16(seh + ga, lds          + slbase[r]);
                gload16(sel + ga, lds + 4096   + slbase[r]);
                gload16(ch  + gc, lds + 8192   + slbase[r]);
                gload16(cl  + gc, lds + 12288  + slbase[r]);
            }
            __syncthreads();

            short8v ah[4], al[4], bh[4], bl[4];
            #pragma unroll
            for (int i = 0; i < 4; ++i) {
                int rowa = wr*64 + i*16 + fr;
                int offa = rowa*32 + ((fq ^ ((rowa >> 1) & 3)) * 8);
                ah[i] = *(const short8v*)(lds + offa);
                al[i] = *(const short8v*)(lds + 4096 + offa);
                int rowb = wc*64 + i*16 + fr;
                int offb = rowb*32 + ((fq ^ ((rowb >> 1) & 3)) * 8);
                bh[i] = *(const short8v*)(lds + 8192 + offb);
                bl[i] = *(const short8v*)(lds + 12288 + offb);
            }
            #pragma unroll
            for (int i = 0; i < 4; ++i)
                #pragma unroll
                for (int jj = 0; jj < 4; ++jj) {
                    acc[i][jj] = __builtin_amdgcn_mfma_f32_16x16x32_bf16(ah[i], bh[jj], acc[i][jj], 0, 0, 0);
                    acc[i][jj] = __builtin_amdgcn_mfma_f32_16x16x32_bf16(ah[i], bl[jj], acc[i][jj], 0, 0, 0);
                    acc[i][jj] = __builtin_amdgcn_mfma_f32_16x16x32_bf16(al[i], bh[jj], acc[i][jj], 0, 0, 0);
                }
        }
        #pragma unroll
        for (int i = 0; i < 4; ++i)
            #pragma unroll
            for (int jj = 0; jj < 4; ++jj) {
                int col = j*128 + wc*64 + jj*16 + fr;
                float cc = c2s[col];
                #pragma unroll
                for (int r = 0; r < 4; ++r) {
                    float d = cc - 2.f * acc[i][jj][r];
                    int s = i*4 + r;
                    if (d < bd[s]) { bd[s] = d; bi[s] = col; }
                }
            }
    }

    #pragma unroll
    for (int s = 0; s < 16; ++s) {
        #pragma unroll
        for (int off = 1; off < 16; off <<= 1) {
            float od = __shfl_xor(bd[s], off);
            int   oi = __shfl_xor(bi[s], off);
            if (od < bd[s] || (od == bd[s] && oi < bi[s])) { bd[s] = od; bi[s] = oi; }
        }
    }
    if (fr == 0) {
        #pragma unroll
        for (int i = 0; i < 4; ++i)
            #pragma unroll
            for (int r = 0; r < 4; ++r) {
                int tl = wr*64 + i*16 + fq*4 + r;
                redD[tl][wc] = bd[i*4 + r];
                redI[tl][wc] = bi[i*4 + r];
            }
    }
    __syncthreads();
    if (tid < 128) {
        float d0 = redD[tid][0], d1 = redD[tid][1];
        int   i0 = redI[tid][0], i1 = redI[tid][1];
        if (d1 < d0 || (d1 == d0 && i1 < i0)) { d0 = d1; i0 = i1; }
        int g = t0 + tid;
        sc[modal*NTOK + g] = i0;
        out_w[OFF_SC + (size_t)modal*NTOK + g] = (float)i0;
    }
}

// ---------------- fp32 fallback assignment ----------------
__global__ __launch_bounds__(256) void k_assign(
    const float* __restrict__ out_ro,
    const float* __restrict__ c2,
    int* __restrict__ sc,
    float* __restrict__ out_w)
{
    const int modal = blockIdx.y;
    const int tok0 = blockIdx.x * 64;
    const float* se   = out_ro + OFF_SE + (size_t)modal * NTOK * 256;
    const float* cent = out_ro + OFF_CENT;

    __shared__ float4 se4[64][64];
    __shared__ float4 ct4[64][64];

    const int tid = threadIdx.x;
    const int tt = tid & 15, cc = tid >> 4;

    {
        int rbase = tid >> 6;
        int d4 = tid & 63;
        #pragma unroll
        for (int i = 0; i < 16; ++i) {
            int t = i*4 + rbase;
            float4 v = *(const float4*)(se + (size_t)(tok0 + t)*256 + d4*4);
            se4[t][d4 ^ (t >> 2)] = v;
        }
    }
    __syncthreads();

    float e2r[4];
    #pragma unroll
    for (int k2 = 0; k2 < 4; ++k2) {
        float s = 0.f;
        for (int d4 = 0; d4 < 64; ++d4) {
            float4 v = se4[4*tt + k2][d4 ^ tt];
            s += dot4(v, v);
        }
        e2r[k2] = s;
    }

    float bd[4]; int bi[4];
    #pragma unroll
    for (int k2 = 0; k2 < 4; ++k2) { bd[k2] = 3.4e38f; bi[k2] = 0; }

    for (int ctile = 0; ctile < 8; ++ctile) {
        int c0 = ctile * 64;
        {
            int rbase = tid >> 6;
            int d4 = tid & 63;
            #pragma unroll
            for (int i = 0; i < 16; ++i) {
                int r = i*4 + rbase;
                float4 v = *(const float4*)(cent + (size_t)(c0 + r)*256 + d4*4);
                ct4[r][d4 ^ (r >> 2)] = v;
            }
        }
        __syncthreads();

        float accd[4][4];
        #pragma unroll
        for (int a = 0; a < 4; ++a)
            #pragma unroll
            for (int b = 0; b < 4; ++b) accd[a][b] = 0.f;

        for (int d4 = 0; d4 < 64; ++d4) {
            float4 sv[4], cv[4];
            #pragma unroll
            for (int k2 = 0; k2 < 4; ++k2) sv[k2] = se4[4*tt + k2][d4 ^ tt];
            #pragma unroll
            for (int jx = 0; jx < 4; ++jx) cv[jx] = ct4[4*cc + jx][d4 ^ cc];
            #pragma unroll
            for (int k2 = 0; k2 < 4; ++k2)
                #pragma unroll
                for (int jx = 0; jx < 4; ++jx)
                    accd[k2][jx] += dot4(sv[k2], cv[jx]);
        }

        #pragma unroll
        for (int jx = 0; jx < 4; ++jx) {
            int cidx = c0 + 4*cc + jx;
            float cj = c2[cidx];
            #pragma unroll
            for (int k2 = 0; k2 < 4; ++k2) {
                float d = cj + e2r[k2] - 2.f * accd[k2][jx];
                if (d < bd[k2]) { bd[k2] = d; bi[k2] = cidx; }
            }
        }
        __syncthreads();
    }

    float* red_d = (float*)ct4;
    int*   red_i = (int*)ct4 + 64*17;
    #pragma unroll
    for (int k2 = 0; k2 < 4; ++k2) {
        red_d[(4*tt + k2)*17 + cc] = bd[k2];
        red_i[(4*tt + k2)*17 + cc] = bi[k2];
    }
    __syncthreads();
    if (tid < 64) {
        float b = red_d[tid*17]; int ix = red_i[tid*17];
        #pragma unroll
        for (int q = 1; q < 16; ++q) {
            float d = red_d[tid*17 + q]; int i2 = red_i[tid*17 + q];
            if (d < b || (d == b && i2 < ix)) { b = d; ix = i2; }
        }
        int g = tok0 + tid;
        sc[modal*NTOK + g] = ix;
        out_w[OFF_SC + (size_t)modal*NTOK + g] = (float)ix;
    }
}

// ---------------- stable counting sort ----------------
__global__ __launch_bounds__(256) void k_hist(const int* __restrict__ sc,
                                              int* __restrict__ blockHist)
{
    int modal = blockIdx.y, blk = blockIdx.x, tid = threadIdx.x;
    __shared__ int h[512];
    h[tid] = 0; h[tid + 256] = 0;
    __syncthreads();
    atomicAdd(&h[sc[modal*NTOK + blk*256 + tid]], 1);
    __syncthreads();
    int base = (modal*128 + blk) * 512;
    blockHist[base + tid]       = h[tid];
    blockHist[base + tid + 256] = h[tid + 256];
}

__global__ __launch_bounds__(512) void k_scan(const int* __restrict__ blockHist,
                                              int* __restrict__ blockBase,
                                              int* __restrict__ classBase,
                                              float* __restrict__ out)
{
    int modal = blockIdx.x;
    int c = threadIdx.x;
    int run = 0;
    for (int b = 0; b < 128; ++b) {
        int idx = (modal*128 + b)*512 + c;
        blockBase[idx] = run;
        run += blockHist[idx];
    }
    float* cnt = out + (modal ? OFF_CI : OFF_CT);
    cnt[c] = (float)run;

    __shared__ int s[512];
    s[c] = run;
    __syncthreads();
    int total = run;
    for (int off = 1; off < 512; off <<= 1) {
        int v = 0;
        if (c >= off) v = s[c - off];
        __syncthreads();
        s[c] += v;
        __syncthreads();
    }
    classBase[modal*512 + c] = s[c] - total;
}

__global__ __launch_bounds__(256) void k_scatter(const int* __restrict__ sc,
                                                 const int* __restrict__ blockBase,
                                                 const int* __restrict__ classBase,
                                                 float* __restrict__ out)
{
    int modal = blockIdx.y, blk = blockIdx.x, tid = threadIdx.x;
    __shared__ int cls[256];
    int t = blk*256 + tid;
    int c = sc[modal*NTOK + t];
    cls[tid] = c;
    __syncthreads();
    int rank = 0;
    for (int j = 0; j < tid; ++j) rank += (cls[j] == c) ? 1 : 0;
    int pos = classBase[modal*512 + c] + blockBase[(modal*128 + blk)*512 + c] + rank;
    float* oo = out + (modal ? OFF_OI : OFF_OT);
    oo[pos] = (float)t;
}

extern "C" void kernel_launch(void* const* d_in, const int* in_sizes, int n_in,
                              void* d_out, int out_size, void* d_ws, size_t ws_size,
                              hipStream_t stream)
{
    const float* text_emb  = (const float*)d_in[0];
    const float* image_emb = (const float*)d_in[1];
    const float* W[2][3] = {
        {(const float*)d_in[2], (const float*)d_in[3], (const float*)d_in[4]},
        {(const float*)d_in[5], (const float*)d_in[6], (const float*)d_in[7]}
    };
    const float* cent_raw = (const float*)d_in[8];
    float* out = (float*)d_out;
    char* w = (char*)d_ws;

    int*   sc        = (int*)w;
    int*   blockHist = (int*)(w + 0x40000);
    int*   blockBase = (int*)(w + 0xC0000);
    int*   classBase = (int*)(w + 0x140000);
    float* c2        = (float*)(w + 0x141000);
    ushort_t* cent_h = (ushort_t*)(w + 0x142000);
    ushort_t* cent_l = (ushort_t*)(w + 0x182000);

    ushort_t* wreg = (ushort_t*)(w + 0x200000);
    const size_t WM = 4*1048576 + 2*262144;

    ushort_t* SEh = (ushort_t*)(w + 0x1400000);
    ushort_t* SEl = (ushort_t*)(w + 0x3400000);

    bool mfmaAssign = true;
    size_t actoff = 0x5400000;
    int Mc = 0;
    for (int c = NTOK; c >= 128; c >>= 1)
        if (actoff + (size_t)c*8192 <= ws_size) { Mc = c; break; }
    if (Mc == 0) {
        mfmaAssign = false;
        actoff = 0x1400000;
        for (int c = NTOK; c >= 128; c >>= 1)
            if (actoff + (size_t)c*8192 <= ws_size) { Mc = c; break; }
        if (Mc == 0) Mc = 128;
    }
    ushort_t* act = (ushort_t*)(w + actoff);
    const bool big = (Mc % 256 == 0);

    k_cent<<<dim3(512), dim3(64), 0, stream>>>(cent_raw, out, c2, cent_h, cent_l);
    k_wc  <<<dim3(64),  dim3(256), 0, stream>>>(out);

    for (int m = 0; m < 2; ++m) {
        const float* emb = m ? image_emb : text_emb;
        ushort_t* w1h = wreg + (size_t)m*WM;
        ushort_t* w1l = w1h + 1048576;
        ushort_t* w2h = w1l + 1048576;
        ushort_t* w2l = w2h + 1048576;
        ushort_t* w3h = w2l + 1048576;
        ushort_t* w3l = w3h + 262144;

        k_wsplit<<<dim3(32, 32), dim3(256), 0, stream>>>(W[m][0], w1h, w1l, 1024, 1024);
        k_wsplit<<<dim3(32, 32), dim3(256), 0, stream>>>(W[m][1], w2h, w2l, 1024, 1024);
        k_wsplit<<<dim3(8,  32), dim3(256), 0, stream>>>(W[m][2], w3h, w3l, 1024, 256);

        ushort_t* Ah = act;
        ushort_t* Al = Ah + (size_t)Mc*1024;
        ushort_t* Hh = Al + (size_t)Mc*1024;
        ushort_t* Hl = Hh + (size_t)Mc*1024;

        for (int s0 = 0; s0 < NTOK; s0 += Mc) {
            if (big) {
                // L1: fused fp32-A split + GEMM (no esplit pass)
                k_gemm_l1<<<dim3((Mc/256)*4), dim3(512), 0, stream>>>(
                    emb + (size_t)s0*1024, w1h, Hh, Hl, 1048576u, 1024);
                k_gemm_mfma256<<<dim3((Mc/256)*4), dim3(512), 0, stream>>>(
                    Hh, w2h, Ah, Al, (unsigned)Mc*1024u, 1048576u, 1024);
            } else {
                long n4 = (long)Mc*1024/4;
                k_esplit<<<dim3((unsigned)((n4 + 255)/256)), dim3(256), 0, stream>>>(
                    emb + (size_t)s0*1024, Ah, Al, n4);
                k_gemm_mfma<<<dim3(8, Mc/128), dim3(256), 0, stream>>>(
                    Ah, Al, w1h, w1l, Hh, Hl, nullptr, 1024);
                k_gemm_mfma<<<dim3(8, Mc/128), dim3(256), 0, stream>>>(
                    Hh, Hl, w2h, w2l, Ah, Al, nullptr, 1024);
            }
            ushort_t* seh_ptr = mfmaAssign ? SEh + ((size_t)m*NTOK + s0)*256 : nullptr;
            ushort_t* sel_ptr = mfmaAssign ? SEl + ((size_t)m*NTOK + s0)*256 : nullptr;
            k_gemm_mfma<<<dim3(2, Mc/128), dim3(256), 0, stream>>>(
                Ah, Al, w3h, w3l, seh_ptr, sel_ptr,
                out + OFF_SE + ((size_t)m*NTOK + s0)*256, 256);
        }
    }

    if (mfmaAssign) {
        k_assign_mfma<<<dim3(256, 2), dim3(256), 0, stream>>>(
            SEh, SEl, cent_h, cent_l, c2, sc, out);
    } else {
        k_assign<<<dim3(512, 2), dim3(256), 0, stream>>>(out, c2, sc, out);
    }
    k_hist   <<<dim3(128, 2), dim3(256), 0, stream>>>(sc, blockHist);
    k_scan   <<<dim3(2),      dim3(512), 0, stream>>>(blockHist, blockBase, classBase, out);
    k_scatter<<<dim3(128, 2), dim3(256), 0, stream>>>(sc, blockBase, classBase, out);
}

// Round 9
// 1041.597 us; speedup vs baseline: 1.1113x; 1.0034x over previous
//
#include <hip/hip_runtime.h>
#include <math.h>

#define NTOK 32768
typedef unsigned short ushort_t;

// d_out offsets (in floats)
#define OFF_CENT 0
#define OFF_SE   131072
#define OFF_WC   16908288
#define OFF_SC   16973824
#define OFF_OT   17039360
#define OFF_CT   17072128
#define OFF_OI   17072640
#define OFF_CI   17105408

typedef __attribute__((ext_vector_type(8))) short short8v;
typedef __attribute__((ext_vector_type(4))) float f32x4;

__device__ __forceinline__ float dot4(float4 a, float4 b){
    return a.x*b.x + a.y*b.y + a.z*b.z + a.w*b.w;
}

// RNE float -> bf16 bits
__device__ __forceinline__ ushort_t f2bf(float x){
    unsigned int u = __float_as_uint(x);
    unsigned int r = (u + 0x7fffu + ((u >> 16) & 1u)) >> 16;
    return (ushort_t)r;
}
__device__ __forceinline__ float bf2f(ushort_t h){
    return __uint_as_float(((unsigned int)h) << 16);
}

__device__ __forceinline__ void gload16(const void* g, void* l){
    __builtin_amdgcn_global_load_lds(
        (const __attribute__((address_space(1))) void*)g,
        (__attribute__((address_space(3))) void*)l,
        16, 0, 0);
}

// split 8 fp32 -> 8 bf16 hi + 8 bf16 lo (bit-identical to esplit)
__device__ __forceinline__ void cvt8(float4 a, float4 b, short8v& h, short8v& l){
    float x[8] = {a.x, a.y, a.z, a.w, b.x, b.y, b.z, b.w};
    #pragma unroll
    for (int i = 0; i < 8; ++i) {
        ushort_t hh = f2bf(x[i]);
        h[i] = (short)hh;
        l[i] = (short)f2bf(x[i] - bf2f(hh));
    }
}

// ---------------- centroids: tanh + c2 + hi/lo split ----------------
__global__ __launch_bounds__(64) void k_cent(const float* __restrict__ raw,
                                             float* __restrict__ out,
                                             float* __restrict__ c2,
                                             ushort_t* __restrict__ ch,
                                             ushort_t* __restrict__ cl)
{
    int c = blockIdx.x, l = threadIdx.x;
    float4 v = *(const float4*)(raw + (size_t)c*256 + l*4);
    float4 t;
    t.x = tanhf(v.x); t.y = tanhf(v.y); t.z = tanhf(v.z); t.w = tanhf(v.w);
    *(float4*)(out + OFF_CENT + (size_t)c*256 + l*4) = t;
    ushort4 h = make_ushort4(f2bf(t.x), f2bf(t.y), f2bf(t.z), f2bf(t.w));
    ushort4 lo = make_ushort4(f2bf(t.x - bf2f(h.x)), f2bf(t.y - bf2f(h.y)),
                              f2bf(t.z - bf2f(h.z)), f2bf(t.w - bf2f(h.w)));
    *(ushort4*)(ch + (size_t)c*256 + l*4) = h;
    *(ushort4*)(cl + (size_t)c*256 + l*4) = lo;
    float s = dot4(t, t);
    #pragma unroll
    for (int off = 32; off > 0; off >>= 1) s += __shfl_down(s, off);
    if (l == 0) c2[c] = s;
}

// ---------------- emb split (fallback path only) ----------------
__global__ __launch_bounds__(256) void k_esplit(const float* __restrict__ x,
                                                ushort_t* __restrict__ hi,
                                                ushort_t* __restrict__ lo,
                                                long n4)
{
    long g = (long)blockIdx.x*256 + threadIdx.x;
    if (g >= n4) return;
    float4 v = ((const float4*)x)[g];
    ushort_t h0 = f2bf(v.x), h1 = f2bf(v.y), h2 = f2bf(v.z), h3 = f2bf(v.w);
    ushort4 h = make_ushort4(h0, h1, h2, h3);
    ushort4 l = make_ushort4(f2bf(v.x - bf2f(h0)), f2bf(v.y - bf2f(h1)),
                             f2bf(v.z - bf2f(h2)), f2bf(v.w - bf2f(h3)));
    ((ushort4*)hi)[g] = h;
    ((ushort4*)lo)[g] = l;
}

// ---------------- weight transpose + split (device body) ----------------
__device__ __forceinline__ void wsplit_tile(const float* __restrict__ W,
                                            ushort_t* __restrict__ Wt_hi,
                                            ushort_t* __restrict__ Wt_lo,
                                            int K, int N, int bx, int by)
{
    __shared__ float t[32][33];
    int k0 = by*32, n0 = bx*32;
    int tx = threadIdx.x & 31, ty = threadIdx.x >> 5;
    #pragma unroll
    for (int r = 0; r < 4; ++r)
        t[ty + r*8][tx] = W[(size_t)(k0 + ty + r*8)*N + n0 + tx];
    __syncthreads();
    #pragma unroll
    for (int r = 0; r < 4; ++r) {
        int n = ty + r*8;
        float x = t[tx][n];
        ushort_t h = f2bf(x);
        Wt_hi[(size_t)(n0+n)*K + k0 + tx] = h;
        Wt_lo[(size_t)(n0+n)*K + k0 + tx] = f2bf(x - bf2f(h));
    }
}

// ---------------- combined prep: all 6 weight splits + word_class ----------------
// blocks 0..4607: wsplit tiles (per modal: W1 1024, W2 1024, W3 256)
// blocks 4608..4671: word_class fill (64 blocks)
__global__ __launch_bounds__(256) void k_prep(
    const float* __restrict__ W1t, const float* __restrict__ W2t, const float* __restrict__ W3t,
    const float* __restrict__ W1i, const float* __restrict__ W2i, const float* __restrict__ W3i,
    ushort_t* __restrict__ wreg, float* __restrict__ out)
{
    const size_t WM = 4*1048576 + 2*262144;
    int b = blockIdx.x;
    if (b >= 4608) {
        int g = (b - 4608)*256 + threadIdx.x;     // 16384 float4s
        float v = (g*4 < NTOK) ? 0.f : 1.f;
        ((float4*)(out + OFF_WC))[g] = make_float4(v, v, v, v);
        return;
    }
    int m = b / 2304;
    int r = b % 2304;
    ushort_t* base = wreg + (size_t)m*WM;
    const float* Ws[3][2] = {{W1t, W1i}, {W2t, W2i}, {W3t, W3i}};
    if (r < 1024) {
        wsplit_tile(Ws[0][m], base, base + 1048576, 1024, 1024, r % 32, r / 32);
    } else if (r < 2048) {
        int r2 = r - 1024;
        wsplit_tile(Ws[1][m], base + 2*1048576, base + 3*1048576, 1024, 1024, r2 % 32, r2 / 32);
    } else {
        int r3 = r - 2048;
        wsplit_tile(Ws[2][m], base + 4*1048576, base + 4*1048576 + 262144, 1024, 256, r3 % 8, r3 / 8);
    }
}

// ================= layer-1: fused fp32-A split + 256x256 split-bf16 GEMM + tanh ======
__global__ __launch_bounds__(512, 2) void k_gemm_l1(
    const float* __restrict__ Af, const ushort_t* __restrict__ Bt_hi,
    ushort_t* __restrict__ C_hi, ushort_t* __restrict__ C_lo,
    unsigned bDelta, int N)
{
    __shared__ ushort_t lds[65536];   // 2 x { Ah Al Bh Bl } each [256][32]

    const int tid  = threadIdx.x;
    const int wave = tid >> 6, lane = tid & 63;
    const int wr = wave >> 2, wc = wave & 3;
    const int fr = lane & 15, fq = lane >> 4;

    int nwg = gridDim.x;
    int id = blockIdx.x;
    if (!(nwg & 7)) { int cpx = nwg >> 3; id = (id & 7)*cpx + (id >> 3); }
    const int nx = N >> 8;
    const int n0 = (id % nx) * 256;
    const int m0 = (id / nx) * 256;

    const int srow0 = tid >> 2;
    const int qx = (tid & 3) ^ ((srow0 >> 1) & 3);

    const float* fA0 = Af + (size_t)(m0 + srow0) * 1024 + qx*8;
    const float* fA1 = fA0 + 131072;
    const unsigned offB0 = (unsigned)(n0 + srow0) * 1024u + (unsigned)qx * 8u;
    const ushort_t* pB0  = Bt_hi + offB0;
    const ushort_t* pB1  = pB0 + 131072u;
    const ushort_t* pB0l = pB0 + bDelta;
    const ushort_t* pB1l = pB1 + bDelta;
    const unsigned ldsS0 = (unsigned)wave * 512u;
    const unsigned ldsS1 = ldsS0 + 4096u;
    const unsigned wOff  = ldsS0 + (unsigned)lane * 8u;

    const unsigned fb = (unsigned)fr*32u + (unsigned)((fq ^ ((fr >> 1) & 3)) * 8);
    const ushort_t* p0 = lds + fb;
    const ushort_t* p1 = p0 + 32768u;

    f32x4 acc[8][4] = {};

#define STGB(KT, WB) { \
    unsigned wb_ = (unsigned)(WB) * 32768u; \
    gload16(pB0  + (KT), lds + wb_ + 16384u + ldsS0); \
    gload16(pB1  + (KT), lds + wb_ + 16384u + ldsS1); \
    gload16(pB0l + (KT), lds + wb_ + 24576u + ldsS0); \
    gload16(pB1l + (KT), lds + wb_ + 24576u + ldsS1); \
}
#define RA1(P, hl, i) (*(const short8v*)((P) + (hl)*8192u + (unsigned)wr*4096u + (unsigned)(i)*512u))
#define RB1(P, hl, j) (*(const short8v*)((P) + 16384u + (hl)*8192u + (unsigned)wc*2048u + (unsigned)(j)*512u))
#define MM16(A8, B8, C4) __builtin_amdgcn_mfma_f32_16x16x32_bf16(A8, B8, C4, 0, 0, 0)

    {
        float4 a00 = *(const float4*)(fA0);
        float4 a01 = *(const float4*)(fA0 + 4);
        float4 a10 = *(const float4*)(fA1);
        float4 a11 = *(const float4*)(fA1 + 4);
        STGB(0, 0);
        short8v h0, l0, h1, l1;
        cvt8(a00, a01, h0, l0);
        cvt8(a10, a11, h1, l1);
        *(short8v*)(lds + wOff)          = h0;
        *(short8v*)(lds + 4096u + wOff)  = h1;
        *(short8v*)(lds + 8192u + wOff)  = l0;
        *(short8v*)(lds + 12288u + wOff) = l1;
    }
    __syncthreads();

    #pragma unroll 1
    for (int kt = 0; kt < 1024; kt += 32) {
        const int par = (kt >> 5) & 1;
        const ushort_t* cp = par ? p1 : p0;
        const bool pf = (kt + 32) < 1024;

        float4 a00, a01, a10, a11;
        if (pf) {
            a00 = *(const float4*)(fA0 + kt + 32);
            a01 = *(const float4*)(fA0 + kt + 36);
            a10 = *(const float4*)(fA1 + kt + 32);
            a11 = *(const float4*)(fA1 + kt + 36);
            STGB(kt + 32, par ^ 1);
        }

        short8v bh0 = RB1(cp,0,0), bl0 = RB1(cp,1,0);
        short8v bh1 = RB1(cp,0,1), bl1 = RB1(cp,1,1);
        short8v bh2 = RB1(cp,0,2), bl2 = RB1(cp,1,2);
        short8v bh3 = RB1(cp,0,3), bl3 = RB1(cp,1,3);

        __builtin_amdgcn_s_setprio(1);
        #pragma unroll
        for (int i = 0; i < 8; ++i) {
            short8v ah = RA1(cp,0,i), al = RA1(cp,1,i);
            acc[i][0] = MM16(ah, bh0, acc[i][0]);
            acc[i][1] = MM16(ah, bh1, acc[i][1]);
            acc[i][2] = MM16(ah, bh2, acc[i][2]);
            acc[i][3] = MM16(ah, bh3, acc[i][3]);
            acc[i][0] = MM16(ah, bl0, acc[i][0]);
            acc[i][1] = MM16(ah, bl1, acc[i][1]);
            acc[i][2] = MM16(ah, bl2, acc[i][2]);
            acc[i][3] = MM16(ah, bl3, acc[i][3]);
            acc[i][0] = MM16(al, bh0, acc[i][0]);
            acc[i][1] = MM16(al, bh1, acc[i][1]);
            acc[i][2] = MM16(al, bh2, acc[i][2]);
            acc[i][3] = MM16(al, bh3, acc[i][3]);
        }
        __builtin_amdgcn_s_setprio(0);

        if (pf) {
            unsigned wb = (unsigned)(par ^ 1) * 32768u;
            short8v h0, l0, h1, l1;
            cvt8(a00, a01, h0, l0);
            cvt8(a10, a11, h1, l1);
            *(short8v*)(lds + wb + wOff)          = h0;
            *(short8v*)(lds + wb + 4096u + wOff)  = h1;
            *(short8v*)(lds + wb + 8192u + wOff)  = l0;
            *(short8v*)(lds + wb + 12288u + wOff) = l1;
        }
        __syncthreads();
    }

    #pragma unroll
    for (int i = 0; i < 8; ++i)
        #pragma unroll
        for (int j = 0; j < 4; ++j)
            #pragma unroll
            for (int r = 0; r < 4; ++r) {
                int row = m0 + wr*128 + i*16 + fq*4 + r;
                int col = n0 + wc*64 + j*16 + fr;
                float t = tanhf(acc[i][j][r]);
                size_t idx = (size_t)row*N + col;
                ushort_t h = f2bf(t);
                C_hi[idx] = h;
                C_lo[idx] = f2bf(t - bf2f(h));
            }
#undef STGB
#undef RA1
#undef RB1
#undef MM16
}

// ================= 256x256 8-wave split-bf16 GEMM + tanh, 16x16x32 MFMA ==========
__global__ __launch_bounds__(512, 2) void k_gemm_mfma256(
    const ushort_t* __restrict__ A_hi, const ushort_t* __restrict__ Bt_hi,
    ushort_t* __restrict__ C_hi, ushort_t* __restrict__ C_lo,
    unsigned aDelta, unsigned bDelta, int N)
{
    __shared__ ushort_t lds[65536];

    const int tid  = threadIdx.x;
    const int wave = tid >> 6, lane = tid & 63;
    const int wr = wave >> 2, wc = wave & 3;
    const int fr = lane & 15, fq = lane >> 4;

    int nwg = gridDim.x;
    int id = blockIdx.x;
    if (!(nwg & 7)) { int cpx = nwg >> 3; id = (id & 7)*cpx + (id >> 3); }
    const int nx = N >> 8;
    const int n0 = (id % nx) * 256;
    const int m0 = (id / nx) * 256;

    const int srow0 = tid >> 2;
    const int qx = (tid & 3) ^ ((srow0 >> 1) & 3);

    const unsigned offA0 = (unsigned)(m0 + srow0) * 1024u + (unsigned)qx * 8u;
    const unsigned offB0 = (unsigned)(n0 + srow0) * 1024u + (unsigned)qx * 8u;
    const ushort_t* pA0  = A_hi + offA0;
    const ushort_t* pA1  = pA0 + 131072u;
    const ushort_t* pA0l = pA0 + aDelta;
    const ushort_t* pA1l = pA1 + aDelta;
    const ushort_t* pB0  = Bt_hi + offB0;
    const ushort_t* pB1  = pB0 + 131072u;
    const ushort_t* pB0l = pB0 + bDelta;
    const ushort_t* pB1l = pB1 + bDelta;
    const unsigned ldsS0 = (unsigned)wave * 512u;
    const unsigned ldsS1 = ldsS0 + 4096u;

    const unsigned fb = (unsigned)fr*32u + (unsigned)((fq ^ ((fr >> 1) & 3)) * 8);
    const ushort_t* p0 = lds + fb;
    const ushort_t* p1 = p0 + 32768u;

    f32x4 acc[8][4] = {};

#define STG(KT, WB) { \
    unsigned wb_ = (unsigned)(WB) * 32768u; \
    gload16(pA0  + (KT), lds + wb_ +           ldsS0); \
    gload16(pA1  + (KT), lds + wb_ +           ldsS1); \
    gload16(pA0l + (KT), lds + wb_ +  8192u +  ldsS0); \
    gload16(pA1l + (KT), lds + wb_ +  8192u +  ldsS1); \
    gload16(pB0  + (KT), lds + wb_ + 16384u +  ldsS0); \
    gload16(pB1  + (KT), lds + wb_ + 16384u +  ldsS1); \
    gload16(pB0l + (KT), lds + wb_ + 24576u +  ldsS0); \
    gload16(pB1l + (KT), lds + wb_ + 24576u +  ldsS1); \
}
#define RA(P, hl, i) (*(const short8v*)((P) + (hl)*8192u + (unsigned)wr*4096u + (unsigned)(i)*512u))
#define RB(P, hl, j) (*(const short8v*)((P) + 16384u + (hl)*8192u + (unsigned)wc*2048u + (unsigned)(j)*512u))
#define MM16(A8, B8, C4) __builtin_amdgcn_mfma_f32_16x16x32_bf16(A8, B8, C4, 0, 0, 0)

    STG(0, 0);
    __syncthreads();

    #pragma unroll 1
    for (int kt = 0; kt < 1024; kt += 32) {
        const int par = (kt >> 5) & 1;
        const ushort_t* cp = par ? p1 : p0;

        short8v bh0 = RB(cp,0,0), bl0 = RB(cp,1,0);
        short8v bh1 = RB(cp,0,1), bl1 = RB(cp,1,1);
        short8v bh2 = RB(cp,0,2), bl2 = RB(cp,1,2);
        short8v bh3 = RB(cp,0,3), bl3 = RB(cp,1,3);

        if (kt + 32 < 1024) STG(kt + 32, par ^ 1);

        __builtin_amdgcn_s_setprio(1);
        #pragma unroll
        for (int i = 0; i < 8; ++i) {
            short8v ah = RA(cp,0,i), al = RA(cp,1,i);
            acc[i][0] = MM16(ah, bh0, acc[i][0]);
            acc[i][1] = MM16(ah, bh1, acc[i][1]);
            acc[i][2] = MM16(ah, bh2, acc[i][2]);
            acc[i][3] = MM16(ah, bh3, acc[i][3]);
            acc[i][0] = MM16(ah, bl0, acc[i][0]);
            acc[i][1] = MM16(ah, bl1, acc[i][1]);
            acc[i][2] = MM16(ah, bl2, acc[i][2]);
            acc[i][3] = MM16(ah, bl3, acc[i][3]);
            acc[i][0] = MM16(al, bh0, acc[i][0]);
            acc[i][1] = MM16(al, bh1, acc[i][1]);
            acc[i][2] = MM16(al, bh2, acc[i][2]);
            acc[i][3] = MM16(al, bh3, acc[i][3]);
        }
        __builtin_amdgcn_s_setprio(0);

        __syncthreads();
    }

    #pragma unroll
    for (int i = 0; i < 8; ++i)
        #pragma unroll
        for (int j = 0; j < 4; ++j)
            #pragma unroll
            for (int r = 0; r < 4; ++r) {
                int row = m0 + wr*128 + i*16 + fq*4 + r;
                int col = n0 + wc*64 + j*16 + fr;
                float t = tanhf(acc[i][j][r]);
                size_t idx = (size_t)row*N + col;
                ushort_t h = f2bf(t);
                C_hi[idx] = h;
                C_lo[idx] = f2bf(t - bf2f(h));
            }
#undef STG
#undef RA
#undef RB
#undef MM16
}

// ---------------- 128x128 split-bf16 MFMA GEMM + tanh (layer 3 / fallback) ----------------
__global__ __launch_bounds__(256, 2) void k_gemm_mfma(
    const ushort_t* __restrict__ A_hi, const ushort_t* __restrict__ A_lo,
    const ushort_t* __restrict__ Bt_hi, const ushort_t* __restrict__ Bt_lo,
    ushort_t* __restrict__ C_hi, ushort_t* __restrict__ C_lo,
    float* __restrict__ Cf,
    int N)
{
    const int K = 1024;
    __shared__ ushort_t lds[16384];

    const int tid  = threadIdx.x;
    const int wave = tid >> 6, lane = tid & 63;
    const int wr = wave >> 1, wc = wave & 1;

    int nwg = gridDim.x * gridDim.y;
    int id = blockIdx.y * gridDim.x + blockIdx.x;
    if (!(nwg & 7)) { int cpx = nwg >> 3; id = (id & 7)*cpx + (id >> 3); }
    const int m0 = (id / gridDim.x) * 128, n0 = (id % gridDim.x) * 128;

    f32x4 acc[4][4] = {};

    int srow[2], sq[2], slbase[2];
    #pragma unroll
    for (int r = 0; r < 2; ++r) {
        int row = wave*32 + r*16 + (lane >> 2);
        srow[r]   = row;
        sq[r]     = (lane & 3) ^ ((row >> 1) & 3);
        slbase[r] = wave*1024 + r*512;
    }

    const int fr = lane & 15, fq = lane >> 4;

    for (int kt = 0; kt < K; kt += 32) {
        __syncthreads();
        #pragma unroll
        for (int r = 0; r < 2; ++r) {
            size_t ga = (size_t)(m0 + srow[r]) * K + kt + sq[r]*8;
            size_t gb = (size_t)(n0 + srow[r]) * K + kt + sq[r]*8;
            gload16(A_hi  + ga, lds          + slbase[r]);
            gload16(A_lo  + ga, lds + 4096   + slbase[r]);
            gload16(Bt_hi + gb, lds + 8192   + slbase[r]);
            gload16(Bt_lo + gb, lds + 12288  + slbase[r]);
        }
        __syncthreads();

        short8v ah[4], al[4], bh[4], bl[4];
        #pragma unroll
        for (int i = 0; i < 4; ++i) {
            int rowa = wr*64 + i*16 + fr;
            int offa = rowa*32 + ((fq ^ ((rowa >> 1) & 3)) * 8);
            ah[i] = *(const short8v*)(lds + offa);
            al[i] = *(const short8v*)(lds + 4096 + offa);
            int rowb = wc*64 + i*16 + fr;
            int offb = rowb*32 + ((fq ^ ((rowb >> 1) & 3)) * 8);
            bh[i] = *(const short8v*)(lds + 8192 + offb);
            bl[i] = *(const short8v*)(lds + 12288 + offb);
        }
        #pragma unroll
        for (int i = 0; i < 4; ++i)
            #pragma unroll
            for (int j = 0; j < 4; ++j) {
                acc[i][j] = __builtin_amdgcn_mfma_f32_16x16x32_bf16(ah[i], bh[j], acc[i][j], 0, 0, 0);
                acc[i][j] = __builtin_amdgcn_mfma_f32_16x16x32_bf16(ah[i], bl[j], acc[i][j], 0, 0, 0);
                acc[i][j] = __builtin_amdgcn_mfma_f32_16x16x32_bf16(al[i], bh[j], acc[i][j], 0, 0, 0);
            }
    }

    #pragma unroll
    for (int i = 0; i < 4; ++i)
        #pragma unroll
        for (int j = 0; j < 4; ++j)
            #pragma unroll
            for (int r = 0; r < 4; ++r) {
                int row = m0 + wr*64 + i*16 + fq*4 + r;
                int col = n0 + wc*64 + j*16 + fr;
                float t = tanhf(acc[i][j][r]);
                size_t idx = (size_t)row*N + col;
                if (Cf) Cf[idx] = t;
                if (C_hi) {
                    ushort_t h = f2bf(t);
                    C_hi[idx] = h;
                    C_lo[idx] = f2bf(t - bf2f(h));
                }
            }
}

// ---------------- MFMA assignment + fused histogram ----------------
__global__ __launch_bounds__(256) void k_assign_mfma(
    const ushort_t* __restrict__ SEh, const ushort_t* __restrict__ SEl,
    const ushort_t* __restrict__ ch, const ushort_t* __restrict__ cl,
    const float* __restrict__ c2,
    int* __restrict__ sc, float* __restrict__ out_w,
    int* __restrict__ blockHist)
{
    __shared__ ushort_t lds[16384];
    __shared__ float c2s[512];
    __shared__ float redD[128][2];
    __shared__ int   redI[128][2];

    const int modal = blockIdx.y;
    const int t0 = blockIdx.x * 128;
    const int tid  = threadIdx.x;
    const int wave = tid >> 6, lane = tid & 63;
    const int wr = wave >> 1, wc = wave & 1;
    const int fr = lane & 15, fq = lane >> 4;

    const ushort_t* seh = SEh + (size_t)modal * NTOK * 256;
    const ushort_t* sel = SEl + (size_t)modal * NTOK * 256;

    c2s[tid] = c2[tid];
    c2s[tid + 256] = c2[tid + 256];

    int srow[2], sq[2], slbase[2];
    #pragma unroll
    for (int r = 0; r < 2; ++r) {
        int row = wave*32 + r*16 + (lane >> 2);
        srow[r]   = row;
        sq[r]     = (lane & 3) ^ ((row >> 1) & 3);
        slbase[r] = wave*1024 + r*512;
    }

    float bd[16]; int bi[16];
    #pragma unroll
    for (int s = 0; s < 16; ++s) { bd[s] = 3.4e38f; bi[s] = 0; }

    for (int j = 0; j < 4; ++j) {
        f32x4 acc[4][4] = {};
        for (int kt = 0; kt < 256; kt += 32) {
            __syncthreads();
            #pragma unroll
            for (int r = 0; r < 2; ++r) {
                size_t ga = (size_t)(t0 + srow[r]) * 256 + kt + sq[r]*8;
                size_t gc = (size_t)(j*128 + srow[r]) * 256 + kt + sq[r]*8;
                gload16(seh + ga, lds          + slbase[r]);
                gload16(sel + ga, lds + 4096   + slbase[r]);
                gload16(ch  + gc, lds + 8192   + slbase[r]);
                gload16(cl  + gc, lds + 12288  + slbase[r]);
            }
            __syncthreads();

            short8v ah[4], al[4], bh[4], bl[4];
            #pragma unroll
            for (int i = 0; i < 4; ++i) {
                int rowa = wr*64 + i*16 + fr;
                int offa = rowa*32 + ((fq ^ ((rowa >> 1) & 3)) * 8);
                ah[i] = *(const short8v*)(lds + offa);
                al[i] = *(const short8v*)(lds + 4096 + offa);
                int rowb = wc*64 + i*16 + fr;
                int offb = rowb*32 + ((fq ^ ((rowb >> 1) & 3)) * 8);
                bh[i] = *(const short8v*)(lds + 8192 + offb);
                bl[i] = *(const short8v*)(lds + 12288 + offb);
            }
            #pragma unroll
            for (int i = 0; i < 4; ++i)
                #pragma unroll
                for (int jj = 0; jj < 4; ++jj) {
                    acc[i][jj] = __builtin_amdgcn_mfma_f32_16x16x32_bf16(ah[i], bh[jj], acc[i][jj], 0, 0, 0);
                    acc[i][jj] = __builtin_amdgcn_mfma_f32_16x16x32_bf16(ah[i], bl[jj], acc[i][jj], 0, 0, 0);
                    acc[i][jj] = __builtin_amdgcn_mfma_f32_16x16x32_bf16(al[i], bh[jj], acc[i][jj], 0, 0, 0);
                }
        }
        #pragma unroll
        for (int i = 0; i < 4; ++i)
            #pragma unroll
            for (int jj = 0; jj < 4; ++jj) {
                int col = j*128 + wc*64 + jj*16 + fr;
                float cc = c2s[col];
                #pragma unroll
                for (int r = 0; r < 4; ++r) {
                    float d = cc - 2.f * acc[i][jj][r];
                    int s = i*4 + r;
                    if (d < bd[s]) { bd[s] = d; bi[s] = col; }
                }
            }
    }

    #pragma unroll
    for (int s = 0; s < 16; ++s) {
        #pragma unroll
        for (int off = 1; off < 16; off <<= 1) {
            float od = __shfl_xor(bd[s], off);
            int   oi = __shfl_xor(bi[s], off);
            if (od < bd[s] || (od == bd[s] && oi < bi[s])) { bd[s] = od; bi[s] = oi; }
        }
    }
    if (fr == 0) {
        #pragma unroll
        for (int i = 0; i < 4; ++i)
            #pragma unroll
            for (int r = 0; r < 4; ++r) {
                int tl = wr*64 + i*16 + fq*4 + r;
                redD[tl][wc] = bd[i*4 + r];
                redI[tl][wc] = bi[i*4 + r];
            }
    }
    __syncthreads();
    if (tid < 128) {
        float d0 = redD[tid][0], d1 = redD[tid][1];
        int   i0 = redI[tid][0], i1 = redI[tid][1];
        if (d1 < d0 || (d1 == d0 && i1 < i0)) { d0 = d1; i0 = i1; }
        int g = t0 + tid;
        sc[modal*NTOK + g] = i0;
        out_w[OFF_SC + (size_t)modal*NTOK + g] = (float)i0;
        atomicAdd(&blockHist[(modal*128 + (g >> 8))*512 + i0], 1);
    }
}

// ---------------- fp32 fallback assignment + fused histogram ----------------
__global__ __launch_bounds__(256) void k_assign(
    const float* __restrict__ out_ro,
    const float* __restrict__ c2,
    int* __restrict__ sc,
    float* __restrict__ out_w,
    int* __restrict__ blockHist)
{
    const int modal = blockIdx.y;
    const int tok0 = blockIdx.x * 64;
    const float* se   = out_ro + OFF_SE + (size_t)modal * NTOK * 256;
    const float* cent = out_ro + OFF_CENT;

    __shared__ float4 se4[64][64];
    __shared__ float4 ct4[64][64];

    const int tid = threadIdx.x;
    const int tt = tid & 15, cc = tid >> 4;

    {
        int rbase = tid >> 6;
        int d4 = tid & 63;
        #pragma unroll
        for (int i = 0; i < 16; ++i) {
            int t = i*4 + rbase;
            float4 v = *(const float4*)(se + (size_t)(tok0 + t)*256 + d4*4);
            se4[t][d4 ^ (t >> 2)] = v;
        }
    }
    __syncthreads();

    float e2r[4];
    #pragma unroll
    for (int k2 = 0; k2 < 4; ++k2) {
        float s = 0.f;
        for (int d4 = 0; d4 < 64; ++d4) {
            float4 v = se4[4*tt + k2][d4 ^ tt];
            s += dot4(v, v);
        }
        e2r[k2] = s;
    }

    float bd[4]; int bi[4];
    #pragma unroll
    for (int k2 = 0; k2 < 4; ++k2) { bd[k2] = 3.4e38f; bi[k2] = 0; }

    for (int ctile = 0; ctile < 8; ++ctile) {
        int c0 = ctile * 64;
        {
            int rbase = tid >> 6;
            int d4 = tid & 63;
            #pragma unroll
            for (int i = 0; i < 16; ++i) {
                int r = i*4 + rbase;
                float4 v = *(const float4*)(cent + (size_t)(c0 + r)*256 + d4*4);
                ct4[r][d4 ^ (r >> 2)] = v;
            }
        }
        __syncthreads();

        float accd[4][4];
        #pragma unroll
        for (int a = 0; a < 4; ++a)
            #pragma unroll
            for (int b = 0; b < 4; ++b) accd[a][b] = 0.f;

        for (int d4 = 0; d4 < 64; ++d4) {
            float4 sv[4], cv[4];
            #pragma unroll
            for (int k2 = 0; k2 < 4; ++k2) sv[k2] = se4[4*tt + k2][d4 ^ tt];
            #pragma unroll
            for (int jx = 0; jx < 4; ++jx) cv[jx] = ct4[4*cc + jx][d4 ^ cc];
            #pragma unroll
            for (int k2 = 0; k2 < 4; ++k2)
                #pragma unroll
                for (int jx = 0; jx < 4; ++jx)
                    accd[k2][jx] += dot4(sv[k2], cv[jx]);
        }

        #pragma unroll
        for (int jx = 0; jx < 4; ++jx) {
            int cidx = c0 + 4*cc + jx;
            float cj = c2[cidx];
            #pragma unroll
            for (int k2 = 0; k2 < 4; ++k2) {
                float d = cj + e2r[k2] - 2.f * accd[k2][jx];
                if (d < bd[k2]) { bd[k2] = d; bi[k2] = cidx; }
            }
        }
        __syncthreads();
    }

    float* red_d = (float*)ct4;
    int*   red_i = (int*)ct4 + 64*17;
    #pragma unroll
    for (int k2 = 0; k2 < 4; ++k2) {
        red_d[(4*tt + k2)*17 + cc] = bd[k2];
        red_i[(4*tt + k2)*17 + cc] = bi[k2];
    }
    __syncthreads();
    if (tid < 64) {
        float b = red_d[tid*17]; int ix = red_i[tid*17];
        #pragma unroll
        for (int q = 1; q < 16; ++q) {
            float d = red_d[tid*17 + q]; int i2 = red_i[tid*17 + q];
            if (d < b || (d == b && i2 < ix)) { b = d; ix = i2; }
        }
        int g = tok0 + tid;
        sc[modal*NTOK + g] = ix;
        out_w[OFF_SC + (size_t)modal*NTOK + g] = (float)ix;
        atomicAdd(&blockHist[(modal*128 + (g >> 8))*512 + ix], 1);
    }
}

// ---------------- per-class block scan + class exclusive scan ----------------
__global__ __launch_bounds__(512) void k_scan(const int* __restrict__ blockHist,
                                              int* __restrict__ blockBase,
                                              int* __restrict__ classBase,
                                              float* __restrict__ out)
{
    int modal = blockIdx.x;
    int c = threadIdx.x;
    int run = 0;
    for (int b = 0; b < 128; ++b) {
        int idx = (modal*128 + b)*512 + c;
        blockBase[idx] = run;
        run += blockHist[idx];
    }
    float* cnt = out + (modal ? OFF_CI : OFF_CT);
    cnt[c] = (float)run;

    __shared__ int s[512];
    s[c] = run;
    __syncthreads();
    int total = run;
    for (int off = 1; off < 512; off <<= 1) {
        int v = 0;
        if (c >= off) v = s[c - off];
        __syncthreads();
        s[c] += v;
        __syncthreads();
    }
    classBase[modal*512 + c] = s[c] - total;
}

__global__ __launch_bounds__(256) void k_scatter(const int* __restrict__ sc,
                                                 const int* __restrict__ blockBase,
                                                 const int* __restrict__ classBase,
                                                 float* __restrict__ out)
{
    int modal = blockIdx.y, blk = blockIdx.x, tid = threadIdx.x;
    __shared__ int cls[256];
    int t = blk*256 + tid;
    int c = sc[modal*NTOK + t];
    cls[tid] = c;
    __syncthreads();
    int rank = 0;
    for (int j = 0; j < tid; ++j) rank += (cls[j] == c) ? 1 : 0;
    int pos = classBase[modal*512 + c] + blockBase[(modal*128 + blk)*512 + c] + rank;
    float* oo = out + (modal ? OFF_OI : OFF_OT);
    oo[pos] = (float)t;
}

extern "C" void kernel_launch(void* const* d_in, const int* in_sizes, int n_in,
                              void* d_out, int out_size, void* d_ws, size_t ws_size,
                              hipStream_t stream)
{
    const float* text_emb  = (const float*)d_in[0];
    const float* image_emb = (const float*)d_in[1];
    const float* W[2][3] = {
        {(const float*)d_in[2], (const float*)d_in[3], (const float*)d_in[4]},
        {(const float*)d_in[5], (const float*)d_in[6], (const float*)d_in[7]}
    };
    const float* cent_raw = (const float*)d_in[8];
    float* out = (float*)d_out;
    char* w = (char*)d_ws;

    int*   sc        = (int*)w;
    int*   blockHist = (int*)(w + 0x40000);
    int*   blockBase = (int*)(w + 0xC0000);
    int*   classBase = (int*)(w + 0x140000);
    float* c2        = (float*)(w + 0x141000);
    ushort_t* cent_h = (ushort_t*)(w + 0x142000);
    ushort_t* cent_l = (ushort_t*)(w + 0x182000);

    ushort_t* wreg = (ushort_t*)(w + 0x200000);
    const size_t WM = 4*1048576 + 2*262144;

    ushort_t* SEh = (ushort_t*)(w + 0x1400000);
    ushort_t* SEl = (ushort_t*)(w + 0x3400000);

    bool mfmaAssign = true;
    size_t actoff = 0x5400000;
    int Mc = 0;
    for (int c = NTOK; c >= 128; c >>= 1)
        if (actoff + (size_t)c*8192 <= ws_size) { Mc = c; break; }
    if (Mc == 0) {
        mfmaAssign = false;
        actoff = 0x1400000;
        for (int c = NTOK; c >= 128; c >>= 1)
            if (actoff + (size_t)c*8192 <= ws_size) { Mc = c; break; }
        if (Mc == 0) Mc = 128;
    }
    ushort_t* act = (ushort_t*)(w + actoff);
    const bool big = (Mc % 256 == 0);

    // zero the fused histogram (deterministic every call)
    hipMemsetAsync(blockHist, 0, 2*128*512*sizeof(int), stream);

    k_cent<<<dim3(512), dim3(64), 0, stream>>>(cent_raw, out, c2, cent_h, cent_l);
    // combined: 6 weight splits + word_class fill
    k_prep<<<dim3(4672), dim3(256), 0, stream>>>(
        W[0][0], W[0][1], W[0][2], W[1][0], W[1][1], W[1][2], wreg, out);

    for (int m = 0; m < 2; ++m) {
        const float* emb = m ? image_emb : text_emb;
        ushort_t* w1h = wreg + (size_t)m*WM;
        ushort_t* w1l = w1h + 1048576;
        ushort_t* w2h = w1l + 1048576;
        ushort_t* w2l = w2h + 1048576;
        ushort_t* w3h = w2l + 1048576;
        ushort_t* w3l = w3h + 262144;

        ushort_t* Ah = act;
        ushort_t* Al = Ah + (size_t)Mc*1024;
        ushort_t* Hh = Al + (size_t)Mc*1024;
        ushort_t* Hl = Hh + (size_t)Mc*1024;

        for (int s0 = 0; s0 < NTOK; s0 += Mc) {
            if (big) {
                k_gemm_l1<<<dim3((Mc/256)*4), dim3(512), 0, stream>>>(
                    emb + (size_t)s0*1024, w1h, Hh, Hl, 1048576u, 1024);
                k_gemm_mfma256<<<dim3((Mc/256)*4), dim3(512), 0, stream>>>(
                    Hh, w2h, Ah, Al, (unsigned)Mc*1024u, 1048576u, 1024);
            } else {
                long n4 = (long)Mc*1024/4;
                k_esplit<<<dim3((unsigned)((n4 + 255)/256)), dim3(256), 0, stream>>>(
                    emb + (size_t)s0*1024, Ah, Al, n4);
                k_gemm_mfma<<<dim3(8, Mc/128), dim3(256), 0, stream>>>(
                    Ah, Al, w1h, w1l, Hh, Hl, nullptr, 1024);
                k_gemm_mfma<<<dim3(8, Mc/128), dim3(256), 0, stream>>>(
                    Hh, Hl, w2h, w2l, Ah, Al, nullptr, 1024);
            }
            ushort_t* seh_ptr = mfmaAssign ? SEh + ((size_t)m*NTOK + s0)*256 : nullptr;
            ushort_t* sel_ptr = mfmaAssign ? SEl + ((size_t)m*NTOK + s0)*256 : nullptr;
            k_gemm_mfma<<<dim3(2, Mc/128), dim3(256), 0, stream>>>(
                Ah, Al, w3h, w3l, seh_ptr, sel_ptr,
                out + OFF_SE + ((size_t)m*NTOK + s0)*256, 256);
        }
    }

    if (mfmaAssign) {
        k_assign_mfma<<<dim3(256, 2), dim3(256), 0, stream>>>(
            SEh, SEl, cent_h, cent_l, c2, sc, out, blockHist);
    } else {
        k_assign<<<dim3(512, 2), dim3(256), 0, stream>>>(out, c2, sc, out, blockHist);
    }
    k_scan   <<<dim3(2),      dim3(512), 0, stream>>>(blockHist, blockBase, classBase, out);
    k_scatter<<<dim3(128, 2), dim3(256), 0, stream>>>(sc, blockBase, classBase, out);
}